// Round 1
// baseline (1201.153 us; speedup 1.0000x reference)
//
#include <hip/hip_runtime.h>
#include <math.h>

// Problem constants (from reference)
#define N_NODES 50000
#define E_EDGES 1600000
#define IN_C    128
#define HID     64
#define OUT_C   40

// ---------------------------------------------------------------------------
// deg[i] = 1.0 (self-loop) + sum_{e: dst==i} w_e
// ---------------------------------------------------------------------------
__global__ __launch_bounds__(256) void k_init_deg(float* __restrict__ deg) {
    int i = blockIdx.x * 256 + threadIdx.x;
    if (i < N_NODES) deg[i] = 1.0f;
}

__global__ __launch_bounds__(256) void k_deg_scatter(const int* __restrict__ ei,
                                                     const float* __restrict__ w,
                                                     float* __restrict__ deg) {
    int e = blockIdx.x * 256 + threadIdx.x;
    if (e < E_EDGES) {
        int d = ei[E_EDGES + e];          // dst row
        atomicAdd(&deg[d], w[e]);
    }
}

__global__ __launch_bounds__(256) void k_dinv(const float* __restrict__ deg,
                                              float* __restrict__ dinv) {
    int i = blockIdx.x * 256 + threadIdx.x;
    if (i < N_NODES) {
        float d = deg[i];
        dinv[i] = (d > 0.0f) ? rsqrtf(d) : 0.0f;
    }
}

// ---------------------------------------------------------------------------
// GEMM + dinv scale, dual write: g = dinv[i] * (act[i] @ W); agg = g (self term)
// Block: 256 threads = 4 nodes x 64 lanes. F_OUT <= 64.
// ---------------------------------------------------------------------------
template <int F_IN, int F_OUT>
__global__ __launch_bounds__(256) void k_gemm_scale(const float* __restrict__ act,
                                                    const float* __restrict__ W,
                                                    const float* __restrict__ dinv,
                                                    float* __restrict__ g,
                                                    float* __restrict__ agg) {
    __shared__ float s_act[4 * F_IN];
    const int tid       = threadIdx.x;
    const int base_node = blockIdx.x * 4;

    // 4 rows of act are contiguous: coalesced cooperative load into LDS.
    for (int idx = tid; idx < 4 * F_IN; idx += 256) {
        s_act[idx] = act[(size_t)base_node * F_IN + idx];
    }
    __syncthreads();

    const int node = base_node + (tid >> 6);
    const int f    = tid & 63;
    if (node >= N_NODES) return;

    float acc = 0.0f;
    if (f < F_OUT) {
        const float* row = &s_act[(tid >> 6) * F_IN];
#pragma unroll 8
        for (int k = 0; k < F_IN; ++k) {
            acc += row[k] * W[k * F_OUT + f];   // W cached (<=32KB), coalesced per wave
        }
        float gv = dinv[node] * acc;
        g[(size_t)node * F_OUT + f]   = gv;
        agg[(size_t)node * F_OUT + f] = gv;     // self-loop contribution
    }
}

// ---------------------------------------------------------------------------
// Edge scatter: agg[dst] += w_e * g[src]. One 64-lane group per edge.
// ---------------------------------------------------------------------------
template <int F_OUT>
__global__ __launch_bounds__(256) void k_scatter(const int* __restrict__ ei,
                                                 const float* __restrict__ w,
                                                 const float* __restrict__ g,
                                                 float* __restrict__ agg) {
    const int idx = blockIdx.x * 256 + threadIdx.x;
    const int e   = idx >> 6;
    const int f   = idx & 63;
    if (e >= E_EDGES) return;

    const int s   = ei[e];               // wave-uniform broadcast loads
    const int d   = ei[E_EDGES + e];
    const float we = w[e];

    if (f < F_OUT) {
        float val = we * g[(size_t)s * F_OUT + f];   // coalesced gather
        atomicAdd(&agg[(size_t)d * F_OUT + f], val); // coalesced atomic
    }
}

// ---------------------------------------------------------------------------
// Post: act = relu(dinv[i]*agg + b)   (layers 1,2)
// ---------------------------------------------------------------------------
template <int F>
__global__ __launch_bounds__(256) void k_post_relu(const float* __restrict__ agg,
                                                   const float* __restrict__ dinv,
                                                   const float* __restrict__ b,
                                                   float* __restrict__ act) {
    const int node = blockIdx.x * 4 + (threadIdx.x >> 6);
    const int f    = threadIdx.x & 63;
    if (node >= N_NODES || f >= F) return;
    float v = dinv[node] * agg[(size_t)node * F + f] + b[f];
    act[(size_t)node * F + f] = fmaxf(v, 0.0f);
}

// ---------------------------------------------------------------------------
// Final: v = relu(dinv*agg + b); out = log_softmax(v) over 40 classes.
// One wave per node; lanes 40..63 padded with -inf / 0.
// ---------------------------------------------------------------------------
__global__ __launch_bounds__(256) void k_final(const float* __restrict__ agg,
                                               const float* __restrict__ dinv,
                                               const float* __restrict__ b,
                                               float* __restrict__ out) {
    const int node = blockIdx.x * 4 + (threadIdx.x >> 6);
    const int f    = threadIdx.x & 63;
    if (node >= N_NODES) return;

    float v = -INFINITY;
    if (f < OUT_C) {
        v = fmaxf(dinv[node] * agg[(size_t)node * OUT_C + f] + b[f], 0.0f);
    }
    // wave max
    float m = v;
#pragma unroll
    for (int off = 32; off > 0; off >>= 1) m = fmaxf(m, __shfl_xor(m, off));
    // wave sum of exp
    float ex = (f < OUT_C) ? expf(v - m) : 0.0f;
    float s = ex;
#pragma unroll
    for (int off = 32; off > 0; off >>= 1) s += __shfl_xor(s, off);

    if (f < OUT_C) {
        out[(size_t)node * OUT_C + f] = v - m - logf(s);
    }
}

// ---------------------------------------------------------------------------
// Launch
// ---------------------------------------------------------------------------
extern "C" void kernel_launch(void* const* d_in, const int* in_sizes, int n_in,
                              void* d_out, int out_size, void* d_ws, size_t ws_size,
                              hipStream_t stream) {
    const float* x   = (const float*)d_in[0];
    const int*   ei  = (const int*)d_in[1];     // [2, E] int
    const float* w   = (const float*)d_in[2];   // [E]
    const float* W1  = (const float*)d_in[3];
    const float* b1  = (const float*)d_in[4];
    const float* W2  = (const float*)d_in[5];
    const float* b2  = (const float*)d_in[6];
    const float* W3  = (const float*)d_in[7];
    const float* b3  = (const float*)d_in[8];
    float* out = (float*)d_out;

    // Workspace carve-up (all regions fully rewritten every call).
    char* ws = (char*)d_ws;
    size_t off = 0;
    auto carve = [&](size_t bytes) {
        char* p = ws + off;
        off += (bytes + 255) & ~(size_t)255;
        return p;
    };
    float* deg  = (float*)carve(N_NODES * sizeof(float));
    float* dinv = (float*)carve(N_NODES * sizeof(float));
    float* bufA = (float*)carve((size_t)N_NODES * 64 * sizeof(float));
    float* bufB = (float*)carve((size_t)N_NODES * 64 * sizeof(float));
    float* bufC = (float*)carve((size_t)N_NODES * OUT_C * sizeof(float));
    (void)ws_size;

    const int nblk_nodes = (N_NODES + 255) / 256;
    const int nblk_edges = (E_EDGES + 255) / 256;
    const int nblk_node4 = (N_NODES + 3) / 4;          // 12500
    const int nblk_scat  = (int)(((size_t)E_EDGES * 64 + 255) / 256); // 400000

    // Degree + dinv
    k_init_deg<<<nblk_nodes, 256, 0, stream>>>(deg);
    k_deg_scatter<<<nblk_edges, 256, 0, stream>>>(ei, w, deg);
    k_dinv<<<nblk_nodes, 256, 0, stream>>>(deg, dinv);

    // Layer 1: x[128] -> 64
    k_gemm_scale<IN_C, HID><<<nblk_node4, 256, 0, stream>>>(x, W1, dinv, bufA, bufB);
    k_scatter<HID><<<nblk_scat, 256, 0, stream>>>(ei, w, bufA, bufB);
    k_post_relu<HID><<<nblk_node4, 256, 0, stream>>>(bufB, dinv, b1, bufA);

    // Layer 2: 64 -> 64 (gemm reads bufA into LDS before writing -> in-place safe)
    k_gemm_scale<HID, HID><<<nblk_node4, 256, 0, stream>>>(bufA, W2, dinv, bufA, bufB);
    k_scatter<HID><<<nblk_scat, 256, 0, stream>>>(ei, w, bufA, bufB);
    k_post_relu<HID><<<nblk_node4, 256, 0, stream>>>(bufB, dinv, b2, bufA);

    // Layer 3: 64 -> 40
    k_gemm_scale<HID, OUT_C><<<nblk_node4, 256, 0, stream>>>(bufA, W3, dinv, bufB, bufC);
    k_scatter<OUT_C><<<nblk_scat, 256, 0, stream>>>(ei, w, bufB, bufC);
    k_final<<<nblk_node4, 256, 0, stream>>>(bufC, dinv, b3, out);
}

// Round 2
// 462.579 us; speedup vs baseline: 2.5966x; 2.5966x over previous
//
#include <hip/hip_runtime.h>
#include <math.h>

#define N_NODES 50000
#define E_EDGES 1600000
#define IN_C    128
#define HID     64
#define OUT_C   40
#define NBLK_SCAN 196   // ceil(50000/256)

// ---------------------------------------------------------------------------
// CSR build: counts -> rowptr (2-level scan) -> fill (int atomic cursor)
// ---------------------------------------------------------------------------
__global__ __launch_bounds__(256) void k_zero_counts(int* __restrict__ counts) {
    int i = blockIdx.x * 256 + threadIdx.x;
    if (i < N_NODES) counts[i] = 0;
}

__global__ __launch_bounds__(256) void k_count(const int* __restrict__ ei,
                                               int* __restrict__ counts) {
    int e = blockIdx.x * 256 + threadIdx.x;
    if (e < E_EDGES) atomicAdd(&counts[ei[E_EDGES + e]], 1);
}

__global__ __launch_bounds__(256) void k_block_sums(const int* __restrict__ counts,
                                                    int* __restrict__ bsum) {
    __shared__ int s[4];
    int i = blockIdx.x * 256 + threadIdx.x;
    int v = (i < N_NODES) ? counts[i] : 0;
#pragma unroll
    for (int off = 32; off > 0; off >>= 1) v += __shfl_xor(v, off);
    if ((threadIdx.x & 63) == 0) s[threadIdx.x >> 6] = v;
    __syncthreads();
    if (threadIdx.x == 0) bsum[blockIdx.x] = s[0] + s[1] + s[2] + s[3];
}

__global__ __launch_bounds__(256) void k_scan_bsums(const int* __restrict__ bsum,
                                                    int* __restrict__ boff) {
    __shared__ int s[256];
    int t = threadIdx.x;
    int v = (t < NBLK_SCAN) ? bsum[t] : 0;
    s[t] = v;
    __syncthreads();
    for (int off = 1; off < 256; off <<= 1) {
        int x = (t >= off) ? s[t - off] : 0;
        __syncthreads();
        s[t] += x;
        __syncthreads();
    }
    if (t < NBLK_SCAN) boff[t] = s[t] - v;   // exclusive
}

__global__ __launch_bounds__(256) void k_emit_rowptr(const int* __restrict__ counts,
                                                     const int* __restrict__ boff,
                                                     int* __restrict__ rowptr) {
    __shared__ int s[256];
    int t = threadIdx.x;
    int i = blockIdx.x * 256 + t;
    int v = (i < N_NODES) ? counts[i] : 0;
    s[t] = v;
    __syncthreads();
    for (int off = 1; off < 256; off <<= 1) {
        int x = (t >= off) ? s[t - off] : 0;
        __syncthreads();
        s[t] += x;
        __syncthreads();
    }
    if (i < N_NODES) rowptr[i] = boff[blockIdx.x] + s[t] - v;
    if (i == 0) rowptr[N_NODES] = E_EDGES;
}

__global__ __launch_bounds__(256) void k_copy_cursor(const int* __restrict__ rowptr,
                                                     int* __restrict__ cursor) {
    int i = blockIdx.x * 256 + threadIdx.x;
    if (i < N_NODES) cursor[i] = rowptr[i];
}

__global__ __launch_bounds__(256) void k_fill(const int* __restrict__ ei,
                                              const float* __restrict__ w,
                                              int* __restrict__ cursor,
                                              int* __restrict__ csr_src,
                                              float* __restrict__ csr_w) {
    int e = blockIdx.x * 256 + threadIdx.x;
    if (e < E_EDGES) {
        int d = ei[E_EDGES + e];
        int pos = atomicAdd(&cursor[d], 1);
        csr_src[pos] = ei[e];
        csr_w[pos]   = w[e];
    }
}

// dinv[i] = rsqrt(1 + sum_row w); one wave per node
__global__ __launch_bounds__(256) void k_dinv_csr(const int* __restrict__ rowptr,
                                                  const float* __restrict__ csr_w,
                                                  float* __restrict__ dinv) {
    int node = blockIdx.x * 4 + (threadIdx.x >> 6);
    int lane = threadIdx.x & 63;
    int beg = rowptr[node], end = rowptr[node + 1];
    float s = 0.0f;
    for (int e = beg + lane; e < end; e += 64) s += csr_w[e];
#pragma unroll
    for (int off = 32; off > 0; off >>= 1) s += __shfl_xor(s, off);
    if (lane == 0) dinv[node] = rsqrtf(1.0f + s);
}

// ---------------------------------------------------------------------------
// Layer-1 GEMM: g = dinv[i] * (x[i] @ W1).  4 nodes x 64 lanes per block.
// ---------------------------------------------------------------------------
__global__ __launch_bounds__(256) void k_gemm1(const float* __restrict__ x,
                                               const float* __restrict__ W,
                                               const float* __restrict__ dinv,
                                               float* __restrict__ g) {
    __shared__ float s_x[4 * IN_C];
    const int tid = threadIdx.x;
    const int base = blockIdx.x * 4;
    for (int idx = tid; idx < 4 * IN_C; idx += 256)
        s_x[idx] = x[(size_t)base * IN_C + idx];
    __syncthreads();
    const int node = base + (tid >> 6);
    const int f = tid & 63;
    const float* row = &s_x[(tid >> 6) * IN_C];
    float acc = 0.0f;
#pragma unroll 8
    for (int k = 0; k < IN_C; ++k) acc += row[k] * W[k * HID + f];
    g[(size_t)node * HID + f] = dinv[node] * acc;
}

// ---------------------------------------------------------------------------
// Fused: aggregate (CSR gather, F=64) + relu(dinv*agg+b) + GEMM to F_OUT
//   g_next = dinv * (act @ W)
// 1 wave per node: 4 edge-groups x 16 lanes x float4; 8 edges in flight.
// ---------------------------------------------------------------------------
template <int F_OUT>
__global__ __launch_bounds__(256) void k_agg_gemm(const int* __restrict__ rowptr,
                                                  const int* __restrict__ csr_src,
                                                  const float* __restrict__ csr_w,
                                                  const float* __restrict__ g,
                                                  const float* __restrict__ dinv,
                                                  const float* __restrict__ bias,
                                                  const float* __restrict__ W,
                                                  float* __restrict__ g_next) {
    __shared__ float s_act[4][HID];
    const int tid  = threadIdx.x;
    const int wv   = tid >> 6;
    const int lane = tid & 63;
    const int node = blockIdx.x * 4 + wv;
    const int grp  = lane >> 4;     // edge group 0..3
    const int sub  = lane & 15;     // feature quad 0..15
    const int beg = rowptr[node], end = rowptr[node + 1];

    float4 acc;
    acc.x = acc.y = acc.z = acc.w = 0.0f;
    if (grp == 0) acc = ((const float4*)&g[(size_t)node * HID])[sub];  // self loop

    int e = beg;
    for (; e + 8 <= end; e += 8) {
        int e0 = e + grp, e1 = e + 4 + grp;
        int s0 = csr_src[e0], s1 = csr_src[e1];
        float w0 = csr_w[e0], w1 = csr_w[e1];
        float4 v0 = ((const float4*)&g[(size_t)s0 * HID])[sub];
        float4 v1 = ((const float4*)&g[(size_t)s1 * HID])[sub];
        acc.x += w0 * v0.x; acc.y += w0 * v0.y; acc.z += w0 * v0.z; acc.w += w0 * v0.w;
        acc.x += w1 * v1.x; acc.y += w1 * v1.y; acc.z += w1 * v1.z; acc.w += w1 * v1.w;
    }
    for (; e < end; e += 4) {
        int myE = e + grp;
        bool a = myE < end;
        int idx = a ? myE : beg;           // beg valid (row non-empty here)
        int sN = csr_src[idx];
        float wN = a ? csr_w[idx] : 0.0f;
        float4 v = ((const float4*)&g[(size_t)sN * HID])[sub];
        acc.x += wN * v.x; acc.y += wN * v.y; acc.z += wN * v.z; acc.w += wN * v.w;
    }
    // reduce across the 4 edge groups
#pragma unroll
    for (int m = 16; m <= 32; m <<= 1) {
        acc.x += __shfl_xor(acc.x, m); acc.y += __shfl_xor(acc.y, m);
        acc.z += __shfl_xor(acc.z, m); acc.w += __shfl_xor(acc.w, m);
    }
    if (grp == 0) {
        float dv = dinv[node];
        float4 b4 = ((const float4*)bias)[sub];
        float4 v;
        v.x = fmaxf(dv * acc.x + b4.x, 0.0f);
        v.y = fmaxf(dv * acc.y + b4.y, 0.0f);
        v.z = fmaxf(dv * acc.z + b4.z, 0.0f);
        v.w = fmaxf(dv * acc.w + b4.w, 0.0f);
        ((float4*)&s_act[wv][0])[sub] = v;
    }
    __syncthreads();
    // GEMM stage: act row (LDS) @ W -> F_OUT, scaled by dinv
    if (lane < F_OUT) {
        float dot = 0.0f;
#pragma unroll
        for (int k = 0; k < HID; ++k) dot += s_act[wv][k] * W[k * F_OUT + lane];
        g_next[(size_t)node * F_OUT + lane] = dinv[node] * dot;
    }
}

// ---------------------------------------------------------------------------
// Final: aggregate (F=40) + relu(dinv*agg+b3) + log_softmax -> out
// ---------------------------------------------------------------------------
__global__ __launch_bounds__(256) void k_final_agg(const int* __restrict__ rowptr,
                                                   const int* __restrict__ csr_src,
                                                   const float* __restrict__ csr_w,
                                                   const float* __restrict__ g,
                                                   const float* __restrict__ dinv,
                                                   const float* __restrict__ bias,
                                                   float* __restrict__ out) {
    const int tid  = threadIdx.x;
    const int wv   = tid >> 6;
    const int lane = tid & 63;
    const int node = blockIdx.x * 4 + wv;
    const int grp  = lane >> 4;
    const int sub  = lane & 15;
    const bool live = sub < (OUT_C / 4);   // 10 quads
    const int beg = rowptr[node], end = rowptr[node + 1];

    float4 acc;
    acc.x = acc.y = acc.z = acc.w = 0.0f;
    if (grp == 0 && live) acc = ((const float4*)&g[(size_t)node * OUT_C])[sub];

    int e = beg;
    for (; e + 8 <= end; e += 8) {
        int e0 = e + grp, e1 = e + 4 + grp;
        int s0 = csr_src[e0], s1 = csr_src[e1];
        float w0 = csr_w[e0], w1 = csr_w[e1];
        if (live) {
            float4 v0 = ((const float4*)&g[(size_t)s0 * OUT_C])[sub];
            float4 v1 = ((const float4*)&g[(size_t)s1 * OUT_C])[sub];
            acc.x += w0 * v0.x; acc.y += w0 * v0.y; acc.z += w0 * v0.z; acc.w += w0 * v0.w;
            acc.x += w1 * v1.x; acc.y += w1 * v1.y; acc.z += w1 * v1.z; acc.w += w1 * v1.w;
        }
    }
    for (; e < end; e += 4) {
        int myE = e + grp;
        bool a = myE < end;
        int idx = a ? myE : beg;
        int sN = csr_src[idx];
        float wN = a ? csr_w[idx] : 0.0f;
        if (live) {
            float4 v = ((const float4*)&g[(size_t)sN * OUT_C])[sub];
            acc.x += wN * v.x; acc.y += wN * v.y; acc.z += wN * v.z; acc.w += wN * v.w;
        }
    }
#pragma unroll
    for (int m = 16; m <= 32; m <<= 1) {
        acc.x += __shfl_xor(acc.x, m); acc.y += __shfl_xor(acc.y, m);
        acc.z += __shfl_xor(acc.z, m); acc.w += __shfl_xor(acc.w, m);
    }

    float dv = dinv[node];
    float4 v; v.x = v.y = v.z = v.w = 0.0f;
    bool own = (grp == 0) && live;
    if (own) {
        float4 b4 = ((const float4*)bias)[sub];
        v.x = fmaxf(dv * acc.x + b4.x, 0.0f);
        v.y = fmaxf(dv * acc.y + b4.y, 0.0f);
        v.z = fmaxf(dv * acc.z + b4.z, 0.0f);
        v.w = fmaxf(dv * acc.w + b4.w, 0.0f);
    }
    // log_softmax across the 40 values held by lanes 0..9 (4 each)
    float m = own ? fmaxf(fmaxf(v.x, v.y), fmaxf(v.z, v.w)) : -INFINITY;
#pragma unroll
    for (int off = 1; off < 16; off <<= 1) m = fmaxf(m, __shfl_xor(m, off));
    float s = own ? (expf(v.x - m) + expf(v.y - m) + expf(v.z - m) + expf(v.w - m)) : 0.0f;
#pragma unroll
    for (int off = 1; off < 16; off <<= 1) s += __shfl_xor(s, off);
    if (own) {
        float lg = m + logf(s);
        float4 o;
        o.x = v.x - lg; o.y = v.y - lg; o.z = v.z - lg; o.w = v.w - lg;
        ((float4*)&out[(size_t)node * OUT_C])[sub] = o;
    }
}

// ---------------------------------------------------------------------------
// Launch
// ---------------------------------------------------------------------------
extern "C" void kernel_launch(void* const* d_in, const int* in_sizes, int n_in,
                              void* d_out, int out_size, void* d_ws, size_t ws_size,
                              hipStream_t stream) {
    const float* x  = (const float*)d_in[0];
    const int*   ei = (const int*)d_in[1];
    const float* w  = (const float*)d_in[2];
    const float* W1 = (const float*)d_in[3];
    const float* b1 = (const float*)d_in[4];
    const float* W2 = (const float*)d_in[5];
    const float* b2 = (const float*)d_in[6];
    const float* W3 = (const float*)d_in[7];
    const float* b3 = (const float*)d_in[8];
    float* out = (float*)d_out;

    char* ws = (char*)d_ws;
    size_t off = 0;
    auto carve = [&](size_t bytes) {
        char* p = ws + off;
        off += (bytes + 255) & ~(size_t)255;
        return p;
    };
    int*   counts  = (int*)carve(N_NODES * sizeof(int));       // reused as cursor
    int*   bsum    = (int*)carve(NBLK_SCAN * sizeof(int));
    int*   boff    = (int*)carve(NBLK_SCAN * sizeof(int));
    int*   rowptr  = (int*)carve((N_NODES + 1) * sizeof(int));
    float* dinv    = (float*)carve(N_NODES * sizeof(float));
    int*   csr_src = (int*)carve((size_t)E_EDGES * sizeof(int));
    float* csr_w   = (float*)carve((size_t)E_EDGES * sizeof(float));
    float* g1      = (float*)carve((size_t)N_NODES * HID * sizeof(float));
    float* g2      = (float*)carve((size_t)N_NODES * HID * sizeof(float));
    float* g3      = g1;   // g1 dead after layer-2 aggregation reads it
    (void)ws_size;

    const int nbN  = (N_NODES + 255) / 256;    // 196
    const int nbE  = (E_EDGES + 255) / 256;    // 6250
    const int nbN4 = N_NODES / 4;              // 12500 (exact)

    // CSR build + dinv
    k_zero_counts<<<nbN, 256, 0, stream>>>(counts);
    k_count<<<nbE, 256, 0, stream>>>(ei, counts);
    k_block_sums<<<NBLK_SCAN, 256, 0, stream>>>(counts, bsum);
    k_scan_bsums<<<1, 256, 0, stream>>>(bsum, boff);
    k_emit_rowptr<<<NBLK_SCAN, 256, 0, stream>>>(counts, boff, rowptr);
    k_copy_cursor<<<nbN, 256, 0, stream>>>(rowptr, counts);    // counts -> cursor
    k_fill<<<nbE, 256, 0, stream>>>(ei, w, counts, csr_src, csr_w);
    k_dinv_csr<<<nbN4, 256, 0, stream>>>(rowptr, csr_w, dinv);

    // Layer 1 GEMM, then fused agg+gemm chain
    k_gemm1<<<nbN4, 256, 0, stream>>>(x, W1, dinv, g1);
    k_agg_gemm<HID><<<nbN4, 256, 0, stream>>>(rowptr, csr_src, csr_w, g1, dinv, b1, W2, g2);
    k_agg_gemm<OUT_C><<<nbN4, 256, 0, stream>>>(rowptr, csr_src, csr_w, g2, dinv, b2, W3, g3);
    k_final_agg<<<nbN4, 256, 0, stream>>>(rowptr, csr_src, csr_w, g3, dinv, b3, out);
}

// Round 3
// 277.656 us; speedup vs baseline: 4.3260x; 1.6660x over previous
//
#include <hip/hip_runtime.h>
#include <math.h>

#define N_NODES 50000
#define E_EDGES 1600000
#define IN_C    128
#define HID     64
#define OUT_C   40

#define BSH     9            // nodes-per-bucket shift
#define BNODES  512          // 1 << BSH
#define NB      98           // ceil(N_NODES / BNODES)
#define CAP     20480        // tmp entries per bucket (mean 16384, sigma ~127)
#define TILE    4096         // edges per block in binning pass
#define P1T     512

typedef unsigned int uint;
typedef unsigned short ushort;

__device__ inline float b2f(ushort h) { return __uint_as_float(((uint)h) << 16); }
__device__ inline ushort f2b(float f) {
    uint u = __float_as_uint(f);
    u += 0x7FFFu + ((u >> 16) & 1u);        // round-to-nearest-even
    return (ushort)(u >> 16);
}

// ---------------------------------------------------------------------------
// CSR build, pass 0: zero the 98 global bucket cursors
// ---------------------------------------------------------------------------
__global__ __launch_bounds__(128) void k_zero_bc(int* __restrict__ bc) {
    if (threadIdx.x < NB) bc[threadIdx.x] = 0;
}

// ---------------------------------------------------------------------------
// Pass 1: bin edges by dst bucket. Per-block LDS histogram + LDS grouping,
// ONE global atomicAdd per (block,bucket), coalesced run-writes to tmp.
// tmp entry: { (dst_local<<16) | src , bits(w) }
// ---------------------------------------------------------------------------
__global__ __launch_bounds__(P1T) void k_bin(const int* __restrict__ ei,
                                             const float* __restrict__ w,
                                             int* __restrict__ bcursor,
                                             uint2* __restrict__ tmp) {
    __shared__ uint2 stage[TILE];             // 32 KB
    __shared__ unsigned char sbuck[TILE];     // 4 KB
    __shared__ int hist[NB], startb[NB], cursor[NB], baseg[NB];
    __shared__ int sc[128];
    const int tid = threadIdx.x;
    const int e0  = blockIdx.x * TILE;
    const int n   = min(TILE, E_EDGES - e0);

    for (int i = tid; i < NB; i += P1T) hist[i] = 0;
    __syncthreads();

    for (int i = tid; i < n; i += P1T) {
        int d = ei[E_EDGES + e0 + i];
        atomicAdd(&hist[d >> BSH], 1);
    }
    __syncthreads();

    // exclusive scan of hist[0..NB) with 128 threads
    if (tid < 128) sc[tid] = (tid < NB) ? hist[tid] : 0;
    __syncthreads();
    for (int off = 1; off < 128; off <<= 1) {
        int x = 0;
        if (tid < 128 && tid >= off) x = sc[tid - off];
        __syncthreads();
        if (tid < 128) sc[tid] += x;
        __syncthreads();
    }
    if (tid < NB) {
        int st = sc[tid] - hist[tid];
        startb[tid] = st;
        cursor[tid] = st;
        baseg[tid]  = atomicAdd(&bcursor[tid], hist[tid]);   // reserve global run
    }
    __syncthreads();

    // group edges by bucket into LDS staging
    for (int i = tid; i < n; i += P1T) {
        int   s  = ei[e0 + i];
        int   d  = ei[E_EDGES + e0 + i];
        float wv = w[e0 + i];
        int   b  = d >> BSH;
        int pos = atomicAdd(&cursor[b], 1);
        stage[pos] = make_uint2(((uint)(d & (BNODES - 1)) << 16) | (uint)s,
                                __float_as_uint(wv));
        sbuck[pos] = (unsigned char)b;
    }
    __syncthreads();

    // coalesced run-writes to per-bucket regions
    for (int i = tid; i < n; i += P1T) {
        int b = sbuck[i];
        int gpos = baseg[b] + (i - startb[b]);
        tmp[(size_t)b * CAP + gpos] = stage[i];
    }
}

// ---------------------------------------------------------------------------
// Scan of the 98 bucket counts -> edge-space base per bucket; rowptr[N]=E
// ---------------------------------------------------------------------------
__global__ __launch_bounds__(128) void k_bucket_scan(const int* __restrict__ bcursor,
                                                     int* __restrict__ ebase,
                                                     int* __restrict__ rowptr) {
    __shared__ int s[128];
    int t = threadIdx.x;
    int v = (t < NB) ? bcursor[t] : 0;
    s[t] = v;
    __syncthreads();
    for (int off = 1; off < 128; off <<= 1) {
        int x = (t >= off) ? s[t - off] : 0;
        __syncthreads();
        s[t] += x;
        __syncthreads();
    }
    if (t < NB) ebase[t] = s[t] - v;
    if (t == 0) rowptr[N_NODES] = E_EDGES;
}

// ---------------------------------------------------------------------------
// Pass 2: per-bucket CSR finalize. LDS node histogram + weighted degree
// (-> dinv), LDS scan -> rowptr slice, LDS cursors -> csr {src,w} (uint2).
// Scattered writes confined to a ~130KB L2-local region.
// ---------------------------------------------------------------------------
__global__ __launch_bounds__(BNODES) void k_build(const int* __restrict__ bcursor,
                                                  const int* __restrict__ ebase,
                                                  const uint2* __restrict__ tmp,
                                                  int* __restrict__ rowptr,
                                                  float* __restrict__ dinv,
                                                  uint2* __restrict__ csr) {
    __shared__ int   hist[BNODES];
    __shared__ float wsum[BNODES];
    __shared__ int   sc[BNODES];
    const int tid = threadIdx.x;
    const int b   = blockIdx.x;
    const int cnt = bcursor[b];
    const int eb  = ebase[b];
    const uint2* tb = tmp + (size_t)b * CAP;

    hist[tid] = 0; wsum[tid] = 0.0f;
    __syncthreads();
    for (int i = tid; i < cnt; i += BNODES) {
        uint2 u = tb[i];
        int dl = u.x >> 16;
        atomicAdd(&hist[dl], 1);
        atomicAdd(&wsum[dl], __uint_as_float(u.y));
    }
    __syncthreads();

    int own = hist[tid];
    sc[tid] = own;
    __syncthreads();
    for (int off = 1; off < BNODES; off <<= 1) {
        int x = (tid >= off) ? sc[tid - off] : 0;
        __syncthreads();
        sc[tid] += x;
        __syncthreads();
    }
    int excl = sc[tid] - own;
    int node = (b << BSH) + tid;
    if (node < N_NODES) {
        rowptr[node] = eb + excl;
        dinv[node]   = rsqrtf(1.0f + wsum[tid]);
    }
    hist[tid] = excl;                 // hist becomes the placement cursor
    __syncthreads();

    for (int i = tid; i < cnt; i += BNODES) {
        uint2 u = tb[i];
        int dl = u.x >> 16;
        int pos = atomicAdd(&hist[dl], 1);
        csr[eb + pos] = make_uint2(u.x & 0xFFFFu, u.y);
    }
}

// ---------------------------------------------------------------------------
// Layer-1 GEMM: g1 = bf16( dinv[i] * (x[i] @ W1) ). 4 nodes x 64 lanes.
// ---------------------------------------------------------------------------
__global__ __launch_bounds__(256) void k_gemm1(const float* __restrict__ x,
                                               const float* __restrict__ W,
                                               const float* __restrict__ dinv,
                                               ushort* __restrict__ g) {
    __shared__ float s_x[4 * IN_C];
    const int tid = threadIdx.x;
    const int base = blockIdx.x * 4;
    for (int idx = tid; idx < 4 * IN_C; idx += 256)
        s_x[idx] = x[(size_t)base * IN_C + idx];
    __syncthreads();
    const int node = base + (tid >> 6);
    const int f = tid & 63;
    const float* row = &s_x[(tid >> 6) * IN_C];
    float acc = 0.0f;
#pragma unroll 8
    for (int k = 0; k < IN_C; ++k) acc += row[k] * W[k * HID + f];
    g[(size_t)node * HID + f] = f2b(dinv[node] * acc);
}

// ---------------------------------------------------------------------------
// Fused: aggregate (bf16 gather, F=64) + relu(dinv*agg+b) + GEMM to F_OUT.
// 1 wave/node: 4 edge-groups x 16 lanes x bf16x4; 8 edges in flight.
// ---------------------------------------------------------------------------
template <int F_OUT>
__global__ __launch_bounds__(256) void k_agg_gemm(const int* __restrict__ rowptr,
                                                  const uint2* __restrict__ csr,
                                                  const ushort* __restrict__ g,
                                                  const float* __restrict__ dinv,
                                                  const float* __restrict__ bias,
                                                  const float* __restrict__ W,
                                                  ushort* __restrict__ g_next) {
    __shared__ float s_act[4][HID];
    const int tid  = threadIdx.x;
    const int wv   = tid >> 6;
    const int lane = tid & 63;
    const int node = blockIdx.x * 4 + wv;
    const int grp  = lane >> 4;
    const int sub  = lane & 15;
    const int beg = rowptr[node], end = rowptr[node + 1];

    float4 acc; acc.x = acc.y = acc.z = acc.w = 0.0f;
    if (grp == 0) {
        ushort4 v = ((const ushort4*)(g + (size_t)node * HID))[sub];
        acc.x = b2f(v.x); acc.y = b2f(v.y); acc.z = b2f(v.z); acc.w = b2f(v.w);
    }

    int e = beg;
    for (; e + 8 <= end; e += 8) {
        uint2 ed0 = csr[e + grp], ed1 = csr[e + 4 + grp];
        ushort4 v0 = ((const ushort4*)(g + (size_t)ed0.x * HID))[sub];
        ushort4 v1 = ((const ushort4*)(g + (size_t)ed1.x * HID))[sub];
        float w0 = __uint_as_float(ed0.y), w1 = __uint_as_float(ed1.y);
        acc.x += w0 * b2f(v0.x) + w1 * b2f(v1.x);
        acc.y += w0 * b2f(v0.y) + w1 * b2f(v1.y);
        acc.z += w0 * b2f(v0.z) + w1 * b2f(v1.z);
        acc.w += w0 * b2f(v0.w) + w1 * b2f(v1.w);
    }
    for (; e < end; e += 4) {
        int myE = e + grp;
        bool a = myE < end;
        uint2 ed = csr[a ? myE : beg];
        float wN = a ? __uint_as_float(ed.y) : 0.0f;
        ushort4 v = ((const ushort4*)(g + (size_t)ed.x * HID))[sub];
        acc.x += wN * b2f(v.x); acc.y += wN * b2f(v.y);
        acc.z += wN * b2f(v.z); acc.w += wN * b2f(v.w);
    }
#pragma unroll
    for (int m = 16; m <= 32; m <<= 1) {
        acc.x += __shfl_xor(acc.x, m); acc.y += __shfl_xor(acc.y, m);
        acc.z += __shfl_xor(acc.z, m); acc.w += __shfl_xor(acc.w, m);
    }
    if (grp == 0) {
        float dv = dinv[node];
        float4 b4 = ((const float4*)bias)[sub];
        float4 v;
        v.x = fmaxf(dv * acc.x + b4.x, 0.0f);
        v.y = fmaxf(dv * acc.y + b4.y, 0.0f);
        v.z = fmaxf(dv * acc.z + b4.z, 0.0f);
        v.w = fmaxf(dv * acc.w + b4.w, 0.0f);
        ((float4*)&s_act[wv][0])[sub] = v;
    }
    __syncthreads();
    if (lane < F_OUT) {
        float dot = 0.0f;
#pragma unroll
        for (int k = 0; k < HID; ++k) dot += s_act[wv][k] * W[k * F_OUT + lane];
        g_next[(size_t)node * F_OUT + lane] = f2b(dinv[node] * dot);
    }
}

// ---------------------------------------------------------------------------
// Final: aggregate (bf16, F=40) + relu(dinv*agg+b3) + log_softmax -> out (f32)
// ---------------------------------------------------------------------------
__global__ __launch_bounds__(256) void k_final_agg(const int* __restrict__ rowptr,
                                                   const uint2* __restrict__ csr,
                                                   const ushort* __restrict__ g,
                                                   const float* __restrict__ dinv,
                                                   const float* __restrict__ bias,
                                                   float* __restrict__ out) {
    const int tid  = threadIdx.x;
    const int wv   = tid >> 6;
    const int lane = tid & 63;
    const int node = blockIdx.x * 4 + wv;
    const int grp  = lane >> 4;
    const int sub  = lane & 15;
    const bool live = sub < (OUT_C / 4);
    const int beg = rowptr[node], end = rowptr[node + 1];

    float4 acc; acc.x = acc.y = acc.z = acc.w = 0.0f;
    if (grp == 0 && live) {
        ushort4 v = ((const ushort4*)(g + (size_t)node * OUT_C))[sub];
        acc.x = b2f(v.x); acc.y = b2f(v.y); acc.z = b2f(v.z); acc.w = b2f(v.w);
    }

    int e = beg;
    for (; e + 8 <= end; e += 8) {
        uint2 ed0 = csr[e + grp], ed1 = csr[e + 4 + grp];
        if (live) {
            ushort4 v0 = ((const ushort4*)(g + (size_t)ed0.x * OUT_C))[sub];
            ushort4 v1 = ((const ushort4*)(g + (size_t)ed1.x * OUT_C))[sub];
            float w0 = __uint_as_float(ed0.y), w1 = __uint_as_float(ed1.y);
            acc.x += w0 * b2f(v0.x) + w1 * b2f(v1.x);
            acc.y += w0 * b2f(v0.y) + w1 * b2f(v1.y);
            acc.z += w0 * b2f(v0.z) + w1 * b2f(v1.z);
            acc.w += w0 * b2f(v0.w) + w1 * b2f(v1.w);
        }
    }
    for (; e < end; e += 4) {
        int myE = e + grp;
        bool a = myE < end;
        uint2 ed = csr[a ? myE : beg];
        float wN = a ? __uint_as_float(ed.y) : 0.0f;
        if (live) {
            ushort4 v = ((const ushort4*)(g + (size_t)ed.x * OUT_C))[sub];
            acc.x += wN * b2f(v.x); acc.y += wN * b2f(v.y);
            acc.z += wN * b2f(v.z); acc.w += wN * b2f(v.w);
        }
    }
#pragma unroll
    for (int m = 16; m <= 32; m <<= 1) {
        acc.x += __shfl_xor(acc.x, m); acc.y += __shfl_xor(acc.y, m);
        acc.z += __shfl_xor(acc.z, m); acc.w += __shfl_xor(acc.w, m);
    }

    float dv = dinv[node];
    float4 v; v.x = v.y = v.z = v.w = 0.0f;
    bool own = (grp == 0) && live;
    if (own) {
        float4 b4 = ((const float4*)bias)[sub];
        v.x = fmaxf(dv * acc.x + b4.x, 0.0f);
        v.y = fmaxf(dv * acc.y + b4.y, 0.0f);
        v.z = fmaxf(dv * acc.z + b4.z, 0.0f);
        v.w = fmaxf(dv * acc.w + b4.w, 0.0f);
    }
    float m = own ? fmaxf(fmaxf(v.x, v.y), fmaxf(v.z, v.w)) : -INFINITY;
#pragma unroll
    for (int off = 1; off < 16; off <<= 1) m = fmaxf(m, __shfl_xor(m, off));
    float s = own ? (expf(v.x - m) + expf(v.y - m) + expf(v.z - m) + expf(v.w - m)) : 0.0f;
#pragma unroll
    for (int off = 1; off < 16; off <<= 1) s += __shfl_xor(s, off);
    if (own) {
        float lg = m + logf(s);
        float4 o;
        o.x = v.x - lg; o.y = v.y - lg; o.z = v.z - lg; o.w = v.w - lg;
        ((float4*)&out[(size_t)node * OUT_C])[sub] = o;
    }
}

// ---------------------------------------------------------------------------
// Launch
// ---------------------------------------------------------------------------
extern "C" void kernel_launch(void* const* d_in, const int* in_sizes, int n_in,
                              void* d_out, int out_size, void* d_ws, size_t ws_size,
                              hipStream_t stream) {
    const float* x  = (const float*)d_in[0];
    const int*   ei = (const int*)d_in[1];
    const float* w  = (const float*)d_in[2];
    const float* W1 = (const float*)d_in[3];
    const float* b1 = (const float*)d_in[4];
    const float* W2 = (const float*)d_in[5];
    const float* b2 = (const float*)d_in[6];
    const float* W3 = (const float*)d_in[7];
    const float* b3 = (const float*)d_in[8];
    float* out = (float*)d_out;

    char* ws = (char*)d_ws;
    size_t off = 0;
    auto carve = [&](size_t bytes) {
        char* p = ws + off;
        off += (bytes + 255) & ~(size_t)255;
        return p;
    };
    int*   bcursor = (int*)carve(NB * sizeof(int));
    int*   ebase   = (int*)carve(NB * sizeof(int));
    int*   rowptr  = (int*)carve((N_NODES + 1) * sizeof(int));
    float* dinv    = (float*)carve(N_NODES * sizeof(float));
    uint2* csr     = (uint2*)carve((size_t)E_EDGES * sizeof(uint2));       // 12.8 MB
    uint2* tmp     = (uint2*)carve((size_t)NB * CAP * sizeof(uint2));      // 16.05 MB
    // tmp is dead after k_build; reuse its region for the bf16 activations
    ushort* g1 = (ushort*)tmp;                       // 6.4 MB
    ushort* g2 = g1 + (size_t)N_NODES * HID;         // 6.4 MB (within tmp's 16 MB)
    ushort* g3 = g1;                                 // g1 dead after layer-2 agg
    (void)ws_size;

    const int nbBin = (E_EDGES + TILE - 1) / TILE;   // 391
    const int nbN4  = N_NODES / 4;                   // 12500 (exact)

    k_zero_bc<<<1, 128, 0, stream>>>(bcursor);
    k_bin<<<nbBin, P1T, 0, stream>>>(ei, w, bcursor, tmp);
    k_bucket_scan<<<1, 128, 0, stream>>>(bcursor, ebase, rowptr);
    k_build<<<NB, BNODES, 0, stream>>>(bcursor, ebase, tmp, rowptr, dinv, csr);

    k_gemm1<<<nbN4, 256, 0, stream>>>(x, W1, dinv, g1);
    k_agg_gemm<HID><<<nbN4, 256, 0, stream>>>(rowptr, csr, g1, dinv, b1, W2, g2);
    k_agg_gemm<OUT_C><<<nbN4, 256, 0, stream>>>(rowptr, csr, g2, dinv, b2, W3, g3);
    k_final_agg<<<nbN4, 256, 0, stream>>>(rowptr, csr, g3, dinv, b3, out);
}

// Round 4
// 253.585 us; speedup vs baseline: 4.7367x; 1.0949x over previous
//
#include <hip/hip_runtime.h>
#include <math.h>

#define N_NODES 50000
#define E_EDGES 1600000
#define IN_C    128
#define HID     64
#define OUT_C   40

#define BSH     9            // nodes-per-bucket shift
#define BNODES  512          // 1 << BSH
#define NB      98           // ceil(N_NODES / BNODES)
#define CAP     20480        // tmp entries per bucket (mean 16384)
#define TILE    4096         // edges per block in binning pass
#define P1T     512
#define NPB     16           // nodes per block in gemm1

typedef unsigned int uint;
typedef unsigned short ushort;

__device__ inline float b2f(ushort h) { return __uint_as_float(((uint)h) << 16); }
__device__ inline ushort f2b(float f) {
    uint u = __float_as_uint(f);
    u += 0x7FFFu + ((u >> 16) & 1u);        // round-to-nearest-even
    return (ushort)(u >> 16);
}

// ---------------------------------------------------------------------------
// Pass 1: bin edges by dst bucket. Per-block LDS histogram + LDS grouping,
// ONE global atomicAdd per (block,bucket), coalesced run-writes to tmp.
// tmp entry: { (dst_local<<16) | src , bits(w_f32) }
// ---------------------------------------------------------------------------
__global__ __launch_bounds__(P1T) void k_bin(const int* __restrict__ ei,
                                             const float* __restrict__ w,
                                             int* __restrict__ bcursor,
                                             uint2* __restrict__ tmp) {
    __shared__ uint2 stage[TILE];             // 32 KB
    __shared__ unsigned char sbuck[TILE];     // 4 KB
    __shared__ int hist[NB], startb[NB], cursor[NB], baseg[NB];
    __shared__ int sc[128];
    const int tid = threadIdx.x;
    const int e0  = blockIdx.x * TILE;
    const int n   = min(TILE, E_EDGES - e0);

    for (int i = tid; i < NB; i += P1T) hist[i] = 0;
    __syncthreads();

    for (int i = tid; i < n; i += P1T) {
        int d = ei[E_EDGES + e0 + i];
        atomicAdd(&hist[d >> BSH], 1);
    }
    __syncthreads();

    if (tid < 128) sc[tid] = (tid < NB) ? hist[tid] : 0;
    __syncthreads();
    for (int off = 1; off < 128; off <<= 1) {
        int x = 0;
        if (tid < 128 && tid >= off) x = sc[tid - off];
        __syncthreads();
        if (tid < 128) sc[tid] += x;
        __syncthreads();
    }
    if (tid < NB) {
        int st = sc[tid] - hist[tid];
        startb[tid] = st;
        cursor[tid] = st;
        baseg[tid]  = atomicAdd(&bcursor[tid], hist[tid]);   // reserve global run
    }
    __syncthreads();

    for (int i = tid; i < n; i += P1T) {
        int   s  = ei[e0 + i];
        int   d  = ei[E_EDGES + e0 + i];
        float wv = w[e0 + i];
        int   b  = d >> BSH;
        int pos = atomicAdd(&cursor[b], 1);
        stage[pos] = make_uint2(((uint)(d & (BNODES - 1)) << 16) | (uint)s,
                                __float_as_uint(wv));
        sbuck[pos] = (unsigned char)b;
    }
    __syncthreads();

    for (int i = tid; i < n; i += P1T) {
        int b = sbuck[i];
        int gpos = baseg[b] + (i - startb[b]);
        tmp[(size_t)b * CAP + gpos] = stage[i];
    }
}

// ---------------------------------------------------------------------------
// Pass 2: per-bucket CSR finalize (in-block bucket scan; no separate kernel).
// csr entry: (bf16(w) << 16) | src   (4 bytes/edge)
// ---------------------------------------------------------------------------
__global__ __launch_bounds__(BNODES) void k_build(const int* __restrict__ bcursor,
                                                  const uint2* __restrict__ tmp,
                                                  int* __restrict__ rowptr,
                                                  float* __restrict__ dinv,
                                                  uint* __restrict__ csr) {
    __shared__ int   hist[BNODES];
    __shared__ float wsum[BNODES];
    __shared__ int   sc[BNODES];
    __shared__ int   sb[128];
    __shared__ int   s_eb;
    const int tid = threadIdx.x;
    const int b   = blockIdx.x;

    if (tid < 128) sb[tid] = (tid < NB) ? bcursor[tid] : 0;
    hist[tid] = 0; wsum[tid] = 0.0f;
    __syncthreads();
    for (int off = 1; off < 128; off <<= 1) {
        int x = (tid < 128 && tid >= off) ? sb[tid - off] : 0;
        __syncthreads();
        if (tid < 128) sb[tid] += x;
        __syncthreads();
    }
    if (tid == 0) s_eb = sb[b] - bcursor[b];   // exclusive bucket base
    __syncthreads();
    const int cnt = bcursor[b];
    const int eb  = s_eb;
    const uint2* tb = tmp + (size_t)b * CAP;

    for (int i = tid; i < cnt; i += BNODES) {
        uint2 u = tb[i];
        int dl = u.x >> 16;
        atomicAdd(&hist[dl], 1);
        atomicAdd(&wsum[dl], __uint_as_float(u.y));
    }
    __syncthreads();

    int own = hist[tid];
    sc[tid] = own;
    __syncthreads();
    for (int off = 1; off < BNODES; off <<= 1) {
        int x = (tid >= off) ? sc[tid - off] : 0;
        __syncthreads();
        sc[tid] += x;
        __syncthreads();
    }
    int excl = sc[tid] - own;
    int node = (b << BSH) + tid;
    if (node < N_NODES) {
        rowptr[node] = eb + excl;
        dinv[node]   = rsqrtf(1.0f + wsum[tid]);
    }
    if (b == 0 && tid == 0) rowptr[N_NODES] = E_EDGES;
    hist[tid] = excl;                 // becomes the placement cursor
    __syncthreads();

    for (int i = tid; i < cnt; i += BNODES) {
        uint2 u = tb[i];
        int dl = u.x >> 16;
        int pos = atomicAdd(&hist[dl], 1);
        csr[eb + pos] = ((uint)f2b(__uint_as_float(u.y)) << 16) | (u.x & 0xFFFFu);
    }
}

// ---------------------------------------------------------------------------
// Layer-1 GEMM: g1 = bf16( dinv[i] * (x[i] @ W1) ). W1 + 16 x-rows in LDS.
// ---------------------------------------------------------------------------
__global__ __launch_bounds__(256) void k_gemm1(const float* __restrict__ x,
                                               const float* __restrict__ W,
                                               const float* __restrict__ dinv,
                                               ushort* __restrict__ g) {
    __shared__ float sW[IN_C * HID];      // 32 KB
    __shared__ float sx[NPB * IN_C];      // 8 KB
    const int tid = threadIdx.x;
    const size_t base = (size_t)blockIdx.x * NPB;

    for (int i = tid; i < (IN_C * HID) / 4; i += 256)
        ((float4*)sW)[i] = ((const float4*)W)[i];
    for (int i = tid; i < (NPB * IN_C) / 4; i += 256)
        ((float4*)sx)[i] = ((const float4*)(x + base * IN_C))[i];
    __syncthreads();

    const int wv = tid >> 6, f = tid & 63;
    for (int nn = 0; nn < 4; ++nn) {
        const int nl = wv * 4 + nn;
        const float* row = &sx[nl * IN_C];
        float acc = 0.0f;
#pragma unroll 8
        for (int k = 0; k < IN_C; k += 4) {
            float4 a = *(const float4*)&row[k];
            acc += a.x * sW[(k + 0) * HID + f] + a.y * sW[(k + 1) * HID + f]
                 + a.z * sW[(k + 2) * HID + f] + a.w * sW[(k + 3) * HID + f];
        }
        const size_t node = base + nl;
        g[node * HID + f] = f2b(dinv[node] * acc);
    }
}

// ---------------------------------------------------------------------------
// Fused: aggregate (bf16 gather, width 64) + relu(dinv*agg+b) + GEMM (LDS W).
// 1 wave/node. 16 edges/iter: coalesced desc load (prefetched 1 iter ahead),
// shfl distribution, 4 independent gathers in flight, predicated tail.
// ---------------------------------------------------------------------------
template <int F_OUT>
__global__ __launch_bounds__(256) void k_agg_gemm(const int* __restrict__ rowptr,
                                                  const uint* __restrict__ csr,
                                                  const ushort* __restrict__ g,
                                                  const float* __restrict__ dinv,
                                                  const float* __restrict__ bias,
                                                  const float* __restrict__ W,
                                                  ushort* __restrict__ g_next) {
    __shared__ float sW[HID * F_OUT];
    __shared__ float s_act[4][HID];
    const int tid  = threadIdx.x;
    for (int i = tid; i < HID * F_OUT; i += 256) sW[i] = W[i];   // sync deferred

    const int wv   = tid >> 6;
    const int lane = tid & 63;
    const int node = blockIdx.x * 4 + wv;
    const int grp  = lane >> 4;     // edge sub-slot group 0..3
    const int sub  = lane & 15;     // feature quad 0..15 (also desc slot)
    const int beg = rowptr[node], end = rowptr[node + 1];

    float4 acc0, acc1;
    acc0.x = acc0.y = acc0.z = acc0.w = 0.0f;
    acc1 = acc0;
    if (grp == 0) {                 // self-loop term
        ushort4 v = ((const ushort4*)(g + (size_t)node * HID))[sub];
        acc0.x = b2f(v.x); acc0.y = b2f(v.y); acc0.z = b2f(v.z); acc0.w = b2f(v.w);
    }

    uint curd = csr[min(beg + sub, E_EDGES - 1)];
    for (int e = beg; e < end; e += 16) {
        uint nextd = csr[min(e + 16 + sub, E_EDGES - 1)];
#pragma unroll
        for (int i = 0; i < 4; ++i) {
            uint d = __shfl(curd, (grp << 4) + 4 * i + grp);
            bool valid = (e + 4 * i + grp) < end;
            float wv2 = valid ? b2f((ushort)(d >> 16)) : 0.0f;
            int srcn = (int)(d & 0xFFFFu);
            ushort4 v = ((const ushort4*)(g + (size_t)srcn * HID))[sub];
            if (i & 1) {
                acc1.x += wv2 * b2f(v.x); acc1.y += wv2 * b2f(v.y);
                acc1.z += wv2 * b2f(v.z); acc1.w += wv2 * b2f(v.w);
            } else {
                acc0.x += wv2 * b2f(v.x); acc0.y += wv2 * b2f(v.y);
                acc0.z += wv2 * b2f(v.z); acc0.w += wv2 * b2f(v.w);
            }
        }
        curd = nextd;
    }
    acc0.x += acc1.x; acc0.y += acc1.y; acc0.z += acc1.z; acc0.w += acc1.w;
#pragma unroll
    for (int m = 16; m <= 32; m <<= 1) {
        acc0.x += __shfl_xor(acc0.x, m); acc0.y += __shfl_xor(acc0.y, m);
        acc0.z += __shfl_xor(acc0.z, m); acc0.w += __shfl_xor(acc0.w, m);
    }
    if (grp == 0) {
        float dv = dinv[node];
        float4 b4 = ((const float4*)bias)[sub];
        float4 v;
        v.x = fmaxf(dv * acc0.x + b4.x, 0.0f);
        v.y = fmaxf(dv * acc0.y + b4.y, 0.0f);
        v.z = fmaxf(dv * acc0.z + b4.z, 0.0f);
        v.w = fmaxf(dv * acc0.w + b4.w, 0.0f);
        ((float4*)&s_act[wv][0])[sub] = v;
    }
    __syncthreads();
    if (lane < F_OUT) {
        float dot = 0.0f;
#pragma unroll 4
        for (int k = 0; k < HID; k += 4) {
            float4 a = *(const float4*)&s_act[wv][k];
            dot += a.x * sW[(k + 0) * F_OUT + lane] + a.y * sW[(k + 1) * F_OUT + lane]
                 + a.z * sW[(k + 2) * F_OUT + lane] + a.w * sW[(k + 3) * F_OUT + lane];
        }
        g_next[(size_t)node * F_OUT + lane] = f2b(dinv[node] * dot);
    }
}

// ---------------------------------------------------------------------------
// Final: aggregate (bf16, width 40) + relu(dinv*agg+b3) + log_softmax -> out
// ---------------------------------------------------------------------------
__global__ __launch_bounds__(256) void k_final_agg(const int* __restrict__ rowptr,
                                                   const uint* __restrict__ csr,
                                                   const ushort* __restrict__ g,
                                                   const float* __restrict__ dinv,
                                                   const float* __restrict__ bias,
                                                   float* __restrict__ out) {
    const int tid  = threadIdx.x;
    const int wv   = tid >> 6;
    const int lane = tid & 63;
    const int node = blockIdx.x * 4 + wv;
    const int grp  = lane >> 4;
    const int sub  = lane & 15;
    const bool live = sub < (OUT_C / 4);
    const int beg = rowptr[node], end = rowptr[node + 1];

    float4 acc0, acc1;
    acc0.x = acc0.y = acc0.z = acc0.w = 0.0f;
    acc1 = acc0;
    if (grp == 0 && live) {
        ushort4 v = ((const ushort4*)(g + (size_t)node * OUT_C))[sub];
        acc0.x = b2f(v.x); acc0.y = b2f(v.y); acc0.z = b2f(v.z); acc0.w = b2f(v.w);
    }

    uint curd = csr[min(beg + sub, E_EDGES - 1)];
    for (int e = beg; e < end; e += 16) {
        uint nextd = csr[min(e + 16 + sub, E_EDGES - 1)];
#pragma unroll
        for (int i = 0; i < 4; ++i) {
            uint d = __shfl(curd, (grp << 4) + 4 * i + grp);
            bool valid = (e + 4 * i + grp) < end;
            float wv2 = valid ? b2f((ushort)(d >> 16)) : 0.0f;
            int srcn = (int)(d & 0xFFFFu);
            if (live) {
                ushort4 v = ((const ushort4*)(g + (size_t)srcn * OUT_C))[sub];
                if (i & 1) {
                    acc1.x += wv2 * b2f(v.x); acc1.y += wv2 * b2f(v.y);
                    acc1.z += wv2 * b2f(v.z); acc1.w += wv2 * b2f(v.w);
                } else {
                    acc0.x += wv2 * b2f(v.x); acc0.y += wv2 * b2f(v.y);
                    acc0.z += wv2 * b2f(v.z); acc0.w += wv2 * b2f(v.w);
                }
            }
        }
        curd = nextd;
    }
    acc0.x += acc1.x; acc0.y += acc1.y; acc0.z += acc1.z; acc0.w += acc1.w;
#pragma unroll
    for (int m = 16; m <= 32; m <<= 1) {
        acc0.x += __shfl_xor(acc0.x, m); acc0.y += __shfl_xor(acc0.y, m);
        acc0.z += __shfl_xor(acc0.z, m); acc0.w += __shfl_xor(acc0.w, m);
    }

    float dv = dinv[node];
    float4 v; v.x = v.y = v.z = v.w = 0.0f;
    bool own = (grp == 0) && live;
    if (own) {
        float4 b4 = ((const float4*)bias)[sub];
        v.x = fmaxf(dv * acc0.x + b4.x, 0.0f);
        v.y = fmaxf(dv * acc0.y + b4.y, 0.0f);
        v.z = fmaxf(dv * acc0.z + b4.z, 0.0f);
        v.w = fmaxf(dv * acc0.w + b4.w, 0.0f);
    }
    float m = own ? fmaxf(fmaxf(v.x, v.y), fmaxf(v.z, v.w)) : -INFINITY;
#pragma unroll
    for (int off = 1; off < 16; off <<= 1) m = fmaxf(m, __shfl_xor(m, off));
    float s = own ? (expf(v.x - m) + expf(v.y - m) + expf(v.z - m) + expf(v.w - m)) : 0.0f;
#pragma unroll
    for (int off = 1; off < 16; off <<= 1) s += __shfl_xor(s, off);
    if (own) {
        float lg = m + logf(s);
        float4 o;
        o.x = v.x - lg; o.y = v.y - lg; o.z = v.z - lg; o.w = v.w - lg;
        ((float4*)&out[(size_t)node * OUT_C])[sub] = o;
    }
}

// ---------------------------------------------------------------------------
// Launch
// ---------------------------------------------------------------------------
extern "C" void kernel_launch(void* const* d_in, const int* in_sizes, int n_in,
                              void* d_out, int out_size, void* d_ws, size_t ws_size,
                              hipStream_t stream) {
    const float* x  = (const float*)d_in[0];
    const int*   ei = (const int*)d_in[1];
    const float* w  = (const float*)d_in[2];
    const float* W1 = (const float*)d_in[3];
    const float* b1 = (const float*)d_in[4];
    const float* W2 = (const float*)d_in[5];
    const float* b2 = (const float*)d_in[6];
    const float* W3 = (const float*)d_in[7];
    const float* b3 = (const float*)d_in[8];
    float* out = (float*)d_out;

    char* ws = (char*)d_ws;
    size_t off = 0;
    auto carve = [&](size_t bytes) {
        char* p = ws + off;
        off += (bytes + 255) & ~(size_t)255;
        return p;
    };
    int*   bcursor = (int*)carve(NB * sizeof(int));
    int*   rowptr  = (int*)carve((N_NODES + 1) * sizeof(int));
    float* dinv    = (float*)carve(N_NODES * sizeof(float));
    uint*  csr     = (uint*)carve((size_t)E_EDGES * sizeof(uint));         // 6.4 MB
    uint2* tmp     = (uint2*)carve((size_t)NB * CAP * sizeof(uint2));      // 16.05 MB
    // tmp dead after k_build; reuse for bf16 activations
    ushort* g1 = (ushort*)tmp;                       // 6.4 MB
    ushort* g2 = g1 + (size_t)N_NODES * HID;         // 6.4 MB
    ushort* g3 = g1;                                 // g1 dead after layer-2 agg
    (void)ws_size;

    const int nbBin = (E_EDGES + TILE - 1) / TILE;   // 391
    const int nbN4  = N_NODES / 4;                   // 12500
    const int nbG1  = N_NODES / NPB;                 // 3125

    hipMemsetAsync(bcursor, 0, NB * sizeof(int), stream);
    k_bin<<<nbBin, P1T, 0, stream>>>(ei, w, bcursor, tmp);
    k_build<<<NB, BNODES, 0, stream>>>(bcursor, tmp, rowptr, dinv, csr);

    k_gemm1<<<nbG1, 256, 0, stream>>>(x, W1, dinv, g1);
    k_agg_gemm<HID><<<nbN4, 256, 0, stream>>>(rowptr, csr, g1, dinv, b1, W2, g2);
    k_agg_gemm<OUT_C><<<nbN4, 256, 0, stream>>>(rowptr, csr, g2, dinv, b2, W3, g3);
    k_final_agg<<<nbN4, 256, 0, stream>>>(rowptr, csr, g3, dinv, b3, out);
}

// Round 5
// 247.082 us; speedup vs baseline: 4.8614x; 1.0263x over previous
//
#include <hip/hip_runtime.h>
#include <math.h>

#define N_NODES 50000
#define E_EDGES 1600000
#define IN_C    128
#define HID     64
#define OUT_C   40

#define BSH     9            // nodes-per-bucket shift
#define BNODES  512          // 1 << BSH
#define NB      98           // ceil(N_NODES / BNODES)
#define CAP     20480        // tmp entries per bucket (mean 16384)
#define TILE    4096         // edges per block in binning pass
#define P1T     512
#define NPB     16           // nodes per block in gemm1

typedef unsigned int uint;
typedef unsigned short ushort;

__device__ inline float b2f(ushort h) { return __uint_as_float(((uint)h) << 16); }
__device__ inline ushort f2b(float f) {
    uint u = __float_as_uint(f);
    u += 0x7FFFu + ((u >> 16) & 1u);        // round-to-nearest-even
    return (ushort)(u >> 16);
}
#define BLO(u) __uint_as_float((u) << 16)
#define BHI(u) __uint_as_float((u) & 0xFFFF0000u)
// v = uint4 of 8 bf16 (features 8s..8s+7); A = feats 0-3, B = feats 4-7
#define FMA8(A, B, v, ww) do { \
    (A).x += (ww) * BLO((v).x); (A).y += (ww) * BHI((v).x); \
    (A).z += (ww) * BLO((v).y); (A).w += (ww) * BHI((v).y); \
    (B).x += (ww) * BLO((v).z); (B).y += (ww) * BHI((v).z); \
    (B).z += (ww) * BLO((v).w); (B).w += (ww) * BHI((v).w); } while (0)

struct EV { uint4 a, b; float wa, wb; };

// issue gathers for 16 edges [ebase, ebase+16): 8-lane groups, lane covers
// edge (ebase + grp) [i=0] and (ebase + 8 + grp) [i=1], feature octet `sub`.
template <int FW>
__device__ __forceinline__ void issue_ev(uint dvec, int ebase, int end,
                                         const ushort* __restrict__ g,
                                         int grp, int sub, EV& E) {
    uint d0 = __shfl(dvec, grp);
    uint d1 = __shfl(dvec, 8 + grp);
    E.wa = (ebase + grp     < end) ? b2f((ushort)(d0 >> 16)) : 0.0f;
    E.wb = (ebase + 8 + grp < end) ? b2f((ushort)(d1 >> 16)) : 0.0f;
    E.a = ((const uint4*)(g + (size_t)(d0 & 0xFFFFu) * FW))[sub];
    E.b = ((const uint4*)(g + (size_t)(d1 & 0xFFFFu) * FW))[sub];
}

// ---------------------------------------------------------------------------
// Pass 1: bin edges by dst bucket (LDS grouping, coalesced run-writes).
// ---------------------------------------------------------------------------
__global__ __launch_bounds__(P1T) void k_bin(const int* __restrict__ ei,
                                             const float* __restrict__ w,
                                             int* __restrict__ bcursor,
                                             uint2* __restrict__ tmp) {
    __shared__ uint2 stage[TILE];             // 32 KB
    __shared__ unsigned char sbuck[TILE];     // 4 KB
    __shared__ int hist[NB], startb[NB], cursor[NB], baseg[NB];
    __shared__ int sc[128];
    const int tid = threadIdx.x;
    const int e0  = blockIdx.x * TILE;
    const int n   = min(TILE, E_EDGES - e0);

    for (int i = tid; i < NB; i += P1T) hist[i] = 0;
    __syncthreads();

    for (int i = tid; i < n; i += P1T) {
        int d = ei[E_EDGES + e0 + i];
        atomicAdd(&hist[d >> BSH], 1);
    }
    __syncthreads();

    if (tid < 128) sc[tid] = (tid < NB) ? hist[tid] : 0;
    __syncthreads();
    for (int off = 1; off < 128; off <<= 1) {
        int x = 0;
        if (tid < 128 && tid >= off) x = sc[tid - off];
        __syncthreads();
        if (tid < 128) sc[tid] += x;
        __syncthreads();
    }
    if (tid < NB) {
        int st = sc[tid] - hist[tid];
        startb[tid] = st;
        cursor[tid] = st;
        baseg[tid]  = atomicAdd(&bcursor[tid], hist[tid]);   // reserve global run
    }
    __syncthreads();

    for (int i = tid; i < n; i += P1T) {
        int   s  = ei[e0 + i];
        int   d  = ei[E_EDGES + e0 + i];
        float wv = w[e0 + i];
        int   b  = d >> BSH;
        int pos = atomicAdd(&cursor[b], 1);
        stage[pos] = make_uint2(((uint)(d & (BNODES - 1)) << 16) | (uint)s,
                                __float_as_uint(wv));
        sbuck[pos] = (unsigned char)b;
    }
    __syncthreads();

    for (int i = tid; i < n; i += P1T) {
        int b = sbuck[i];
        int gpos = baseg[b] + (i - startb[b]);
        tmp[(size_t)b * CAP + gpos] = stage[i];
    }
}

// ---------------------------------------------------------------------------
// Pass 2: per-bucket CSR finalize. csr entry: (bf16(w)<<16) | src
// ---------------------------------------------------------------------------
__global__ __launch_bounds__(BNODES) void k_build(const int* __restrict__ bcursor,
                                                  const uint2* __restrict__ tmp,
                                                  int* __restrict__ rowptr,
                                                  float* __restrict__ dinv,
                                                  uint* __restrict__ csr) {
    __shared__ int   hist[BNODES];
    __shared__ float wsum[BNODES];
    __shared__ int   sc[BNODES];
    __shared__ int   sb[128];
    __shared__ int   s_eb;
    const int tid = threadIdx.x;
    const int b   = blockIdx.x;

    if (tid < 128) sb[tid] = (tid < NB) ? bcursor[tid] : 0;
    hist[tid] = 0; wsum[tid] = 0.0f;
    __syncthreads();
    for (int off = 1; off < 128; off <<= 1) {
        int x = (tid < 128 && tid >= off) ? sb[tid - off] : 0;
        __syncthreads();
        if (tid < 128) sb[tid] += x;
        __syncthreads();
    }
    if (tid == 0) s_eb = sb[b] - bcursor[b];   // exclusive bucket base
    __syncthreads();
    const int cnt = bcursor[b];
    const int eb  = s_eb;
    const uint2* tb = tmp + (size_t)b * CAP;

    for (int i = tid; i < cnt; i += BNODES) {
        uint2 u = tb[i];
        int dl = u.x >> 16;
        atomicAdd(&hist[dl], 1);
        atomicAdd(&wsum[dl], __uint_as_float(u.y));
    }
    __syncthreads();

    int own = hist[tid];
    sc[tid] = own;
    __syncthreads();
    for (int off = 1; off < BNODES; off <<= 1) {
        int x = (tid >= off) ? sc[tid - off] : 0;
        __syncthreads();
        sc[tid] += x;
        __syncthreads();
    }
    int excl = sc[tid] - own;
    int node = (b << BSH) + tid;
    if (node < N_NODES) {
        rowptr[node] = eb + excl;
        dinv[node]   = rsqrtf(1.0f + wsum[tid]);
    }
    if (b == 0 && tid == 0) rowptr[N_NODES] = E_EDGES;
    hist[tid] = excl;                 // becomes the placement cursor
    __syncthreads();

    for (int i = tid; i < cnt; i += BNODES) {
        uint2 u = tb[i];
        int dl = u.x >> 16;
        int pos = atomicAdd(&hist[dl], 1);
        csr[eb + pos] = ((uint)f2b(__uint_as_float(u.y)) << 16) | (u.x & 0xFFFFu);
    }
}

// ---------------------------------------------------------------------------
// Layer-1 GEMM: g1 = bf16( dinv[i] * (x[i] @ W1) ). W1 + 16 x-rows in LDS.
// ---------------------------------------------------------------------------
__global__ __launch_bounds__(256) void k_gemm1(const float* __restrict__ x,
                                               const float* __restrict__ W,
                                               const float* __restrict__ dinv,
                                               ushort* __restrict__ g) {
    __shared__ float sW[IN_C * HID];      // 32 KB
    __shared__ float sx[NPB * IN_C];      // 8 KB
    const int tid = threadIdx.x;
    const size_t base = (size_t)blockIdx.x * NPB;

    for (int i = tid; i < (IN_C * HID) / 4; i += 256)
        ((float4*)sW)[i] = ((const float4*)W)[i];
    for (int i = tid; i < (NPB * IN_C) / 4; i += 256)
        ((float4*)sx)[i] = ((const float4*)(x + base * IN_C))[i];
    __syncthreads();

    const int wv = tid >> 6, f = tid & 63;
    for (int nn = 0; nn < 4; ++nn) {
        const int nl = wv * 4 + nn;
        const float* row = &sx[nl * IN_C];
        float acc = 0.0f;
#pragma unroll 8
        for (int k = 0; k < IN_C; k += 4) {
            float4 a = *(const float4*)&row[k];
            acc += a.x * sW[(k + 0) * HID + f] + a.y * sW[(k + 1) * HID + f]
                 + a.z * sW[(k + 2) * HID + f] + a.w * sW[(k + 3) * HID + f];
        }
        const size_t node = base + nl;
        g[node * HID + f] = f2b(dinv[node] * acc);
    }
}

// ---------------------------------------------------------------------------
// Fused: aggregate (bf16 gather, width 64) + relu(dinv*agg+b) + GEMM (LDS W).
// 1 wave/node; 8-lane edge groups x ushort8; depth-2 value pipeline.
// ---------------------------------------------------------------------------
template <int F_OUT>
__global__ __launch_bounds__(256) void k_agg_gemm(const int* __restrict__ rowptr,
                                                  const uint* __restrict__ csr,
                                                  const ushort* __restrict__ g,
                                                  const float* __restrict__ dinv,
                                                  const float* __restrict__ bias,
                                                  const float* __restrict__ W,
                                                  ushort* __restrict__ g_next) {
    __shared__ float sW[HID * F_OUT];
    __shared__ float s_act[4][HID];
    const int tid = threadIdx.x;
    for (int i = tid; i < HID * F_OUT; i += 256) sW[i] = W[i];   // sync deferred

    const int wv = tid >> 6, lane = tid & 63;
    const int node  = blockIdx.x * 4 + wv;
    const int grp   = lane >> 3;      // edge slot 0..7
    const int sub   = lane & 7;       // feature octet (16 B)
    const int dslot = lane & 15;      // descriptor slot
    const int beg = rowptr[node], end = rowptr[node + 1];
    const float dv = dinv[node];

    float4 accA = {0.f, 0.f, 0.f, 0.f}, accB = accA;
    if (grp == 0) {                   // self-loop term, weight 1
        uint4 v = ((const uint4*)(g + (size_t)node * HID))[sub];
        accA.x = BLO(v.x); accA.y = BHI(v.x); accA.z = BLO(v.y); accA.w = BHI(v.y);
        accB.x = BLO(v.z); accB.y = BHI(v.z); accB.z = BLO(v.w); accB.w = BHI(v.w);
    }

    if (beg < end) {
        uint dv0 = csr[min(beg      + dslot, E_EDGES - 1)];
        uint dv1 = csr[min(beg + 16 + dslot, E_EDGES - 1)];
        uint dv2 = csr[min(beg + 32 + dslot, E_EDGES - 1)];
        EV E0, E1, En;
        issue_ev<HID>(dv0, beg,      end, g, grp, sub, E0);
        issue_ev<HID>(dv1, beg + 16, end, g, grp, sub, E1);
        for (int e = beg; e < end; e += 16) {
            issue_ev<HID>(dv2, e + 32, end, g, grp, sub, En);
            dv2 = csr[min(e + 48 + dslot, E_EDGES - 1)];
            FMA8(accA, accB, E0.a, E0.wa);
            FMA8(accA, accB, E0.b, E0.wb);
            E0 = E1; E1 = En;
        }
    }
#pragma unroll
    for (int m = 8; m <= 32; m <<= 1) {
        accA.x += __shfl_xor(accA.x, m); accA.y += __shfl_xor(accA.y, m);
        accA.z += __shfl_xor(accA.z, m); accA.w += __shfl_xor(accA.w, m);
        accB.x += __shfl_xor(accB.x, m); accB.y += __shfl_xor(accB.y, m);
        accB.z += __shfl_xor(accB.z, m); accB.w += __shfl_xor(accB.w, m);
    }
    if (grp == 0) {
        float4 bA = ((const float4*)bias)[2 * sub];
        float4 bB = ((const float4*)bias)[2 * sub + 1];
        float4 rA, rB;
        rA.x = fmaxf(dv * accA.x + bA.x, 0.f); rA.y = fmaxf(dv * accA.y + bA.y, 0.f);
        rA.z = fmaxf(dv * accA.z + bA.z, 0.f); rA.w = fmaxf(dv * accA.w + bA.w, 0.f);
        rB.x = fmaxf(dv * accB.x + bB.x, 0.f); rB.y = fmaxf(dv * accB.y + bB.y, 0.f);
        rB.z = fmaxf(dv * accB.z + bB.z, 0.f); rB.w = fmaxf(dv * accB.w + bB.w, 0.f);
        ((float4*)&s_act[wv][0])[2 * sub]     = rA;
        ((float4*)&s_act[wv][0])[2 * sub + 1] = rB;
    }
    __syncthreads();
    if (lane < F_OUT) {
        float dot = 0.0f;
#pragma unroll 4
        for (int k = 0; k < HID; k += 4) {
            float4 a = *(const float4*)&s_act[wv][k];
            dot += a.x * sW[(k + 0) * F_OUT + lane] + a.y * sW[(k + 1) * F_OUT + lane]
                 + a.z * sW[(k + 2) * F_OUT + lane] + a.w * sW[(k + 3) * F_OUT + lane];
        }
        g_next[(size_t)node * F_OUT + lane] = f2b(dinv[node] * dot);
    }
}

// ---------------------------------------------------------------------------
// Final: aggregate (bf16, width 40) + relu(dinv*agg+b3) + log_softmax -> out
// Same 8-lane pipeline; sub<5 lanes live (5 x 16B = 80B row).
// ---------------------------------------------------------------------------
__global__ __launch_bounds__(256) void k_final_agg(const int* __restrict__ rowptr,
                                                   const uint* __restrict__ csr,
                                                   const ushort* __restrict__ g,
                                                   const float* __restrict__ dinv,
                                                   const float* __restrict__ bias,
                                                   float* __restrict__ out) {
    const int tid = threadIdx.x;
    const int wv = tid >> 6, lane = tid & 63;
    const int node  = blockIdx.x * 4 + wv;
    const int grp   = lane >> 3;
    const int sub   = lane & 7;
    const int dslot = lane & 15;
    const bool live = sub < (OUT_C / 8);   // 5 octets of 8 feats
    const int beg = rowptr[node], end = rowptr[node + 1];
    const float dv = dinv[node];

    float4 accA = {0.f, 0.f, 0.f, 0.f}, accB = accA;
    if (grp == 0 && live) {
        uint4 v = ((const uint4*)(g + (size_t)node * OUT_C))[sub];
        accA.x = BLO(v.x); accA.y = BHI(v.x); accA.z = BLO(v.y); accA.w = BHI(v.y);
        accB.x = BLO(v.z); accB.y = BHI(v.z); accB.z = BLO(v.w); accB.w = BHI(v.w);
    }

    if (beg < end) {
        uint dv0 = csr[min(beg      + dslot, E_EDGES - 1)];
        uint dv1 = csr[min(beg + 16 + dslot, E_EDGES - 1)];
        uint dv2 = csr[min(beg + 32 + dslot, E_EDGES - 1)];
        EV E0, E1, En;
        issue_ev<OUT_C>(dv0, beg,      end, g, grp, sub, E0);
        issue_ev<OUT_C>(dv1, beg + 16, end, g, grp, sub, E1);
        for (int e = beg; e < end; e += 16) {
            issue_ev<OUT_C>(dv2, e + 32, end, g, grp, sub, En);
            dv2 = csr[min(e + 48 + dslot, E_EDGES - 1)];
            FMA8(accA, accB, E0.a, E0.wa);
            FMA8(accA, accB, E0.b, E0.wb);
            E0 = E1; E1 = En;
        }
    }
#pragma unroll
    for (int m = 8; m <= 32; m <<= 1) {
        accA.x += __shfl_xor(accA.x, m); accA.y += __shfl_xor(accA.y, m);
        accA.z += __shfl_xor(accA.z, m); accA.w += __shfl_xor(accA.w, m);
        accB.x += __shfl_xor(accB.x, m); accB.y += __shfl_xor(accB.y, m);
        accB.z += __shfl_xor(accB.z, m); accB.w += __shfl_xor(accB.w, m);
    }

    const bool own = (grp == 0) && live;
    float4 vA = {0.f, 0.f, 0.f, 0.f}, vB = vA;
    if (own) {
        float4 bA = ((const float4*)bias)[2 * sub];
        float4 bB = ((const float4*)bias)[2 * sub + 1];
        vA.x = fmaxf(dv * accA.x + bA.x, 0.f); vA.y = fmaxf(dv * accA.y + bA.y, 0.f);
        vA.z = fmaxf(dv * accA.z + bA.z, 0.f); vA.w = fmaxf(dv * accA.w + bA.w, 0.f);
        vB.x = fmaxf(dv * accB.x + bB.x, 0.f); vB.y = fmaxf(dv * accB.y + bB.y, 0.f);
        vB.z = fmaxf(dv * accB.z + bB.z, 0.f); vB.w = fmaxf(dv * accB.w + bB.w, 0.f);
    }
    float mx = own ? fmaxf(fmaxf(fmaxf(vA.x, vA.y), fmaxf(vA.z, vA.w)),
                           fmaxf(fmaxf(vB.x, vB.y), fmaxf(vB.z, vB.w))) : -INFINITY;
#pragma unroll
    for (int off = 1; off < 8; off <<= 1) mx = fmaxf(mx, __shfl_xor(mx, off));
    float se = own ? (expf(vA.x - mx) + expf(vA.y - mx) + expf(vA.z - mx) + expf(vA.w - mx)
                    + expf(vB.x - mx) + expf(vB.y - mx) + expf(vB.z - mx) + expf(vB.w - mx)) : 0.f;
#pragma unroll
    for (int off = 1; off < 8; off <<= 1) se += __shfl_xor(se, off);
    if (own) {
        float lg = mx + logf(se);
        float4 oA, oB;
        oA.x = vA.x - lg; oA.y = vA.y - lg; oA.z = vA.z - lg; oA.w = vA.w - lg;
        oB.x = vB.x - lg; oB.y = vB.y - lg; oB.z = vB.z - lg; oB.w = vB.w - lg;
        ((float4*)(out + (size_t)node * OUT_C))[2 * sub]     = oA;
        ((float4*)(out + (size_t)node * OUT_C))[2 * sub + 1] = oB;
    }
}

// ---------------------------------------------------------------------------
// Launch
// ---------------------------------------------------------------------------
extern "C" void kernel_launch(void* const* d_in, const int* in_sizes, int n_in,
                              void* d_out, int out_size, void* d_ws, size_t ws_size,
                              hipStream_t stream) {
    const float* x  = (const float*)d_in[0];
    const int*   ei = (const int*)d_in[1];
    const float* w  = (const float*)d_in[2];
    const float* W1 = (const float*)d_in[3];
    const float* b1 = (const float*)d_in[4];
    const float* W2 = (const float*)d_in[5];
    const float* b2 = (const float*)d_in[6];
    const float* W3 = (const float*)d_in[7];
    const float* b3 = (const float*)d_in[8];
    float* out = (float*)d_out;

    char* ws = (char*)d_ws;
    size_t off = 0;
    auto carve = [&](size_t bytes) {
        char* p = ws + off;
        off += (bytes + 255) & ~(size_t)255;
        return p;
    };
    int*   bcursor = (int*)carve(NB * sizeof(int));
    int*   rowptr  = (int*)carve((N_NODES + 1) * sizeof(int));
    float* dinv    = (float*)carve(N_NODES * sizeof(float));
    uint*  csr     = (uint*)carve((size_t)E_EDGES * sizeof(uint));         // 6.4 MB
    uint2* tmp     = (uint2*)carve((size_t)NB * CAP * sizeof(uint2));      // 16.05 MB
    // tmp dead after k_build; reuse for bf16 activations
    ushort* g1 = (ushort*)tmp;                       // 6.4 MB
    ushort* g2 = g1 + (size_t)N_NODES * HID;         // 6.4 MB
    ushort* g3 = g1;                                 // g1 dead after layer-2 agg
    (void)ws_size;

    const int nbBin = (E_EDGES + TILE - 1) / TILE;   // 391
    const int nbN4  = N_NODES / 4;                   // 12500
    const int nbG1  = N_NODES / NPB;                 // 3125

    hipMemsetAsync(bcursor, 0, NB * sizeof(int), stream);
    k_bin<<<nbBin, P1T, 0, stream>>>(ei, w, bcursor, tmp);
    k_build<<<NB, BNODES, 0, stream>>>(bcursor, tmp, rowptr, dinv, csr);

    k_gemm1<<<nbG1, 256, 0, stream>>>(x, W1, dinv, g1);
    k_agg_gemm<HID><<<nbN4, 256, 0, stream>>>(rowptr, csr, g1, dinv, b1, W2, g2);
    k_agg_gemm<OUT_C><<<nbN4, 256, 0, stream>>>(rowptr, csr, g2, dinv, b2, W3, g3);
    k_final_agg<<<nbN4, 256, 0, stream>>>(rowptr, csr, g3, dinv, b3, out);
}

// Round 6
// 242.567 us; speedup vs baseline: 4.9518x; 1.0186x over previous
//
#include <hip/hip_runtime.h>
#include <math.h>

#define N_NODES 50000
#define E_EDGES 1600000
#define IN_C    128
#define HID     64
#define OUT_C   40

#define BSH     9            // nodes-per-bucket shift
#define BNODES  512          // 1 << BSH
#define NB      98           // ceil(N_NODES / BNODES)
#define CAP     20480        // tmp entries per bucket (mean 16384, max ~16.9k)
#define PBS     28160        // padded csr stride per bucket (CAP + 512*15)
#define TILE    4096         // edges per block in binning pass
#define P1T     512
#define NPB     16           // nodes per block in gemm1

typedef unsigned int uint;
typedef unsigned short ushort;

__device__ inline float b2f(ushort h) { return __uint_as_float(((uint)h) << 16); }
__device__ inline ushort f2b(float f) {
    uint u = __float_as_uint(f);
    u += 0x7FFFu + ((u >> 16) & 1u);        // round-to-nearest-even
    return (ushort)(u >> 16);
}
#define BLO(u) __uint_as_float((u) << 16)
#define BHI(u) __uint_as_float((u) & 0xFFFF0000u)
// v = uint4 of 8 bf16 (features 8s..8s+7); A = feats 0-3, B = feats 4-7
#define FMA8(A, B, v, ww) do { \
    (A).x += (ww) * BLO((v).x); (A).y += (ww) * BHI((v).x); \
    (A).z += (ww) * BLO((v).y); (A).w += (ww) * BHI((v).y); \
    (B).x += (ww) * BLO((v).z); (B).y += (ww) * BHI((v).z); \
    (B).z += (ww) * BLO((v).w); (B).w += (ww) * BHI((v).w); } while (0)

// ---------------------------------------------------------------------------
// Pass 1: bin edges by dst bucket (LDS grouping, coalesced run-writes).
// tmp entry: { (dst_local<<16) | src , bits(w_f32) }
// ---------------------------------------------------------------------------
__global__ __launch_bounds__(P1T) void k_bin(const int* __restrict__ ei,
                                             const float* __restrict__ w,
                                             int* __restrict__ bcursor,
                                             uint2* __restrict__ tmp) {
    __shared__ uint2 stage[TILE];             // 32 KB
    __shared__ unsigned char sbuck[TILE];     // 4 KB
    __shared__ int hist[NB], startb[NB], cursor[NB], baseg[NB];
    __shared__ int sc[128];
    const int tid = threadIdx.x;
    const int e0  = blockIdx.x * TILE;
    const int n   = min(TILE, E_EDGES - e0);

    for (int i = tid; i < NB; i += P1T) hist[i] = 0;
    __syncthreads();

    for (int i = tid; i < n; i += P1T) {
        int d = ei[E_EDGES + e0 + i];
        atomicAdd(&hist[d >> BSH], 1);
    }
    __syncthreads();

    if (tid < 128) sc[tid] = (tid < NB) ? hist[tid] : 0;
    __syncthreads();
    for (int off = 1; off < 128; off <<= 1) {
        int x = 0;
        if (tid < 128 && tid >= off) x = sc[tid - off];
        __syncthreads();
        if (tid < 128) sc[tid] += x;
        __syncthreads();
    }
    if (tid < NB) {
        int st = sc[tid] - hist[tid];
        startb[tid] = st;
        cursor[tid] = st;
        baseg[tid]  = atomicAdd(&bcursor[tid], hist[tid]);   // reserve global run
    }
    __syncthreads();

    for (int i = tid; i < n; i += P1T) {
        int   s  = ei[e0 + i];
        int   d  = ei[E_EDGES + e0 + i];
        float wv = w[e0 + i];
        int   b  = d >> BSH;
        int pos = atomicAdd(&cursor[b], 1);
        stage[pos] = make_uint2(((uint)(d & (BNODES - 1)) << 16) | (uint)s,
                                __float_as_uint(wv));
        sbuck[pos] = (unsigned char)b;
    }
    __syncthreads();

    for (int i = tid; i < n; i += P1T) {
        int b = sbuck[i];
        int gpos = baseg[b] + (i - startb[b]);
        tmp[(size_t)b * CAP + gpos] = stage[i];
    }
}

// ---------------------------------------------------------------------------
// Pass 2: per-bucket CSR finalize with 16-PADDED rows.
// csr entry: (bf16(w)<<16) | src ; pad entries are 0 (w=0, src=0).
// rowinfo[node] = (n_16blocks << 24) | row_start  (start 16-aligned).
// ---------------------------------------------------------------------------
__global__ __launch_bounds__(BNODES) void k_build(const int* __restrict__ bcursor,
                                                  const uint2* __restrict__ tmp,
                                                  uint* __restrict__ rowinfo,
                                                  float* __restrict__ dinv,
                                                  uint* __restrict__ csr) {
    __shared__ int   hist[BNODES];
    __shared__ float wsum[BNODES];
    __shared__ int   sc[BNODES];
    __shared__ int   cur[BNODES];
    const int tid = threadIdx.x;
    const int b   = blockIdx.x;
    const int cnt = bcursor[b];
    const uint2* tb = tmp + (size_t)b * CAP;

    hist[tid] = 0; wsum[tid] = 0.0f;
    __syncthreads();
    for (int i = tid; i < cnt; i += BNODES) {
        uint2 u = tb[i];
        int dl = u.x >> 16;
        atomicAdd(&hist[dl], 1);
        atomicAdd(&wsum[dl], __uint_as_float(u.y));
    }
    __syncthreads();

    const int deg  = hist[tid];
    const int pdeg = (deg + 15) & ~15;
    sc[tid] = pdeg;
    __syncthreads();
    for (int off = 1; off < BNODES; off <<= 1) {
        int x = (tid >= off) ? sc[tid - off] : 0;
        __syncthreads();
        sc[tid] += x;
        __syncthreads();
    }
    const int base = b * PBS + (sc[tid] - pdeg);   // 16-aligned row start
    const int node = (b << BSH) + tid;
    if (node < N_NODES) {
        rowinfo[node] = ((uint)(pdeg >> 4) << 24) | (uint)base;
        dinv[node]    = rsqrtf(1.0f + wsum[tid]);
    }
    cur[tid] = base;                  // placement cursor (real entries)
    __syncthreads();

    for (int i = tid; i < cnt; i += BNODES) {
        uint2 u = tb[i];
        int dl = u.x >> 16;
        int pos = atomicAdd(&cur[dl], 1);
        csr[pos] = ((uint)f2b(__uint_as_float(u.y)) << 16) | (u.x & 0xFFFFu);
    }
    // zero-weight pads for the row tail
    for (int i = deg; i < pdeg; ++i) csr[base + i] = 0u;
}

// ---------------------------------------------------------------------------
// Layer-1 GEMM: g1 = bf16( dinv[i] * (x[i] @ W1) ). W1 + 16 x-rows in LDS.
// ---------------------------------------------------------------------------
__global__ __launch_bounds__(256) void k_gemm1(const float* __restrict__ x,
                                               const float* __restrict__ W,
                                               const float* __restrict__ dinv,
                                               ushort* __restrict__ g) {
    __shared__ float sW[IN_C * HID];      // 32 KB
    __shared__ float sx[NPB * IN_C];      // 8 KB
    const int tid = threadIdx.x;
    const size_t base = (size_t)blockIdx.x * NPB;

    for (int i = tid; i < (IN_C * HID) / 4; i += 256)
        ((float4*)sW)[i] = ((const float4*)W)[i];
    for (int i = tid; i < (NPB * IN_C) / 4; i += 256)
        ((float4*)sx)[i] = ((const float4*)(x + base * IN_C))[i];
    __syncthreads();

    const int wv = tid >> 6, f = tid & 63;
    for (int nn = 0; nn < 4; ++nn) {
        const int nl = wv * 4 + nn;
        const float* row = &sx[nl * IN_C];
        float acc = 0.0f;
#pragma unroll 8
        for (int k = 0; k < IN_C; k += 4) {
            float4 a = *(const float4*)&row[k];
            acc += a.x * sW[(k + 0) * HID + f] + a.y * sW[(k + 1) * HID + f]
                 + a.z * sW[(k + 2) * HID + f] + a.w * sW[(k + 3) * HID + f];
        }
        const size_t node = base + nl;
        g[node * HID + f] = f2b(dinv[node] * acc);
    }
}

// ---------------------------------------------------------------------------
// Fused: aggregate (bf16 gather, width 64) + relu(dinv*agg+b) + GEMM (LDS W).
// Branchless padded rows: 8-lane edge groups x ushort8, named double-buffer.
// ---------------------------------------------------------------------------
template <int F_OUT>
__global__ __launch_bounds__(256) void k_agg_gemm(const uint* __restrict__ rowinfo,
                                                  const uint* __restrict__ csr,
                                                  const ushort* __restrict__ g,
                                                  const float* __restrict__ dinv,
                                                  const float* __restrict__ bias,
                                                  const float* __restrict__ W,
                                                  ushort* __restrict__ g_next) {
    __shared__ float sW[HID * F_OUT];
    __shared__ float s_act[4][HID];
    const int tid = threadIdx.x;
    for (int i = tid; i < HID * F_OUT; i += 256) sW[i] = W[i];   // sync deferred

    const int wv = tid >> 6, lane = tid & 63;
    const int node  = blockIdx.x * 4 + wv;
    const int grp   = lane >> 3;      // edge sub-slot 0..7
    const int sub   = lane & 7;       // feature octet (16 B)
    const int dslot = lane & 15;      // descriptor slot
    const uint ri  = rowinfo[node];
    const int  n16 = (int)(ri >> 24);
    const float dv = dinv[node];
    const ushort* gs = g + (size_t)sub * 8;

    float4 accA = {0.f, 0.f, 0.f, 0.f}, accB = accA;
    if (grp == 0) {                   // self-loop term, weight 1
        uint4 v = ((const uint4*)(g + (size_t)node * HID))[sub];
        accA.x = BLO(v.x); accA.y = BHI(v.x); accA.z = BLO(v.y); accA.w = BHI(v.y);
        accB.x = BLO(v.z); accB.y = BHI(v.z); accB.z = BLO(v.w); accB.w = BHI(v.w);
    }

    if (n16 > 0) {
        const uint* rp = csr + (ri & 0xFFFFFFu) + dslot;
        uint d1 = rp[0];
        uint sA = __shfl(d1, grp), sB = __shfl(d1, 8 + grp);
        float wA = BHI(sA), wB = BHI(sB);
        uint4 A = *(const uint4*)(gs + (size_t)(sA & 0xFFFFu) * HID);
        uint4 B = *(const uint4*)(gs + (size_t)(sB & 0xFFFFu) * HID);
        d1 = rp[16];
        for (int blk = 1; blk < n16; ++blk) {
            uint d2 = rp[(blk + 1) << 4];         // last iter: in-bounds garbage, unused
            uint sA2 = __shfl(d1, grp), sB2 = __shfl(d1, 8 + grp);
            float wA2 = BHI(sA2), wB2 = BHI(sB2);
            uint4 A2 = *(const uint4*)(gs + (size_t)(sA2 & 0xFFFFu) * HID);
            uint4 B2 = *(const uint4*)(gs + (size_t)(sB2 & 0xFFFFu) * HID);
            FMA8(accA, accB, A, wA);
            FMA8(accA, accB, B, wB);
            d1 = d2; A = A2; B = B2; wA = wA2; wB = wB2;
        }
        FMA8(accA, accB, A, wA);
        FMA8(accA, accB, B, wB);
    }
#pragma unroll
    for (int m = 8; m <= 32; m <<= 1) {
        accA.x += __shfl_xor(accA.x, m); accA.y += __shfl_xor(accA.y, m);
        accA.z += __shfl_xor(accA.z, m); accA.w += __shfl_xor(accA.w, m);
        accB.x += __shfl_xor(accB.x, m); accB.y += __shfl_xor(accB.y, m);
        accB.z += __shfl_xor(accB.z, m); accB.w += __shfl_xor(accB.w, m);
    }
    if (grp == 0) {
        float4 bA = ((const float4*)bias)[2 * sub];
        float4 bB = ((const float4*)bias)[2 * sub + 1];
        float4 rA, rB;
        rA.x = fmaxf(dv * accA.x + bA.x, 0.f); rA.y = fmaxf(dv * accA.y + bA.y, 0.f);
        rA.z = fmaxf(dv * accA.z + bA.z, 0.f); rA.w = fmaxf(dv * accA.w + bA.w, 0.f);
        rB.x = fmaxf(dv * accB.x + bB.x, 0.f); rB.y = fmaxf(dv * accB.y + bB.y, 0.f);
        rB.z = fmaxf(dv * accB.z + bB.z, 0.f); rB.w = fmaxf(dv * accB.w + bB.w, 0.f);
        ((float4*)&s_act[wv][0])[2 * sub]     = rA;
        ((float4*)&s_act[wv][0])[2 * sub + 1] = rB;
    }
    __syncthreads();
    if (lane < F_OUT) {
        float dot = 0.0f;
#pragma unroll 4
        for (int k = 0; k < HID; k += 4) {
            float4 a = *(const float4*)&s_act[wv][k];
            dot += a.x * sW[(k + 0) * F_OUT + lane] + a.y * sW[(k + 1) * F_OUT + lane]
                 + a.z * sW[(k + 2) * F_OUT + lane] + a.w * sW[(k + 3) * F_OUT + lane];
        }
        g_next[(size_t)node * F_OUT + lane] = f2b(dinv[node] * dot);
    }
}

// ---------------------------------------------------------------------------
// Final: aggregate (bf16, width 40) + relu(dinv*agg+b3) + log_softmax -> out
// Same branchless pipeline; sub<5 lanes hold live features.
// ---------------------------------------------------------------------------
__global__ __launch_bounds__(256) void k_final_agg(const uint* __restrict__ rowinfo,
                                                   const uint* __restrict__ csr,
                                                   const ushort* __restrict__ g,
                                                   const float* __restrict__ dinv,
                                                   const float* __restrict__ bias,
                                                   float* __restrict__ out) {
    const int tid = threadIdx.x;
    const int wv = tid >> 6, lane = tid & 63;
    const int node  = blockIdx.x * 4 + wv;
    const int grp   = lane >> 3;
    const int sub   = lane & 7;
    const int dslot = lane & 15;
    const bool live = sub < (OUT_C / 8);   // 5 octets of 8 feats
    const uint ri  = rowinfo[node];
    const int  n16 = (int)(ri >> 24);
    const float dv = dinv[node];
    const ushort* gs = g + (size_t)sub * 8;

    float4 accA = {0.f, 0.f, 0.f, 0.f}, accB = accA;
    if (grp == 0 && live) {
        uint4 v = ((const uint4*)(g + (size_t)node * OUT_C))[sub];
        accA.x = BLO(v.x); accA.y = BHI(v.x); accA.z = BLO(v.y); accA.w = BHI(v.y);
        accB.x = BLO(v.z); accB.y = BHI(v.z); accB.z = BLO(v.w); accB.w = BHI(v.w);
    }

    if (n16 > 0) {
        const uint* rp = csr + (ri & 0xFFFFFFu) + dslot;
        uint d1 = rp[0];
        uint sA = __shfl(d1, grp), sB = __shfl(d1, 8 + grp);
        float wA = BHI(sA), wB = BHI(sB);
        uint4 A = *(const uint4*)(gs + (size_t)(sA & 0xFFFFu) * OUT_C);
        uint4 B = *(const uint4*)(gs + (size_t)(sB & 0xFFFFu) * OUT_C);
        d1 = rp[16];
        for (int blk = 1; blk < n16; ++blk) {
            uint d2 = rp[(blk + 1) << 4];
            uint sA2 = __shfl(d1, grp), sB2 = __shfl(d1, 8 + grp);
            float wA2 = BHI(sA2), wB2 = BHI(sB2);
            uint4 A2 = *(const uint4*)(gs + (size_t)(sA2 & 0xFFFFu) * OUT_C);
            uint4 B2 = *(const uint4*)(gs + (size_t)(sB2 & 0xFFFFu) * OUT_C);
            FMA8(accA, accB, A, wA);
            FMA8(accA, accB, B, wB);
            d1 = d2; A = A2; B = B2; wA = wA2; wB = wB2;
        }
        FMA8(accA, accB, A, wA);
        FMA8(accA, accB, B, wB);
    }
#pragma unroll
    for (int m = 8; m <= 32; m <<= 1) {
        accA.x += __shfl_xor(accA.x, m); accA.y += __shfl_xor(accA.y, m);
        accA.z += __shfl_xor(accA.z, m); accA.w += __shfl_xor(accA.w, m);
        accB.x += __shfl_xor(accB.x, m); accB.y += __shfl_xor(accB.y, m);
        accB.z += __shfl_xor(accB.z, m); accB.w += __shfl_xor(accB.w, m);
    }

    const bool own = (grp == 0) && live;
    float4 vA = {0.f, 0.f, 0.f, 0.f}, vB = vA;
    if (own) {
        float4 bA = ((const float4*)bias)[2 * sub];
        float4 bB = ((const float4*)bias)[2 * sub + 1];
        vA.x = fmaxf(dv * accA.x + bA.x, 0.f); vA.y = fmaxf(dv * accA.y + bA.y, 0.f);
        vA.z = fmaxf(dv * accA.z + bA.z, 0.f); vA.w = fmaxf(dv * accA.w + bA.w, 0.f);
        vB.x = fmaxf(dv * accB.x + bB.x, 0.f); vB.y = fmaxf(dv * accB.y + bB.y, 0.f);
        vB.z = fmaxf(dv * accB.z + bB.z, 0.f); vB.w = fmaxf(dv * accB.w + bB.w, 0.f);
    }
    float mx = own ? fmaxf(fmaxf(fmaxf(vA.x, vA.y), fmaxf(vA.z, vA.w)),
                           fmaxf(fmaxf(vB.x, vB.y), fmaxf(vB.z, vB.w))) : -INFINITY;
#pragma unroll
    for (int off = 1; off < 8; off <<= 1) mx = fmaxf(mx, __shfl_xor(mx, off));
    float se = own ? (expf(vA.x - mx) + expf(vA.y - mx) + expf(vA.z - mx) + expf(vA.w - mx)
                    + expf(vB.x - mx) + expf(vB.y - mx) + expf(vB.z - mx) + expf(vB.w - mx)) : 0.f;
#pragma unroll
    for (int off = 1; off < 8; off <<= 1) se += __shfl_xor(se, off);
    if (own) {
        float lg = mx + logf(se);
        float4 oA, oB;
        oA.x = vA.x - lg; oA.y = vA.y - lg; oA.z = vA.z - lg; oA.w = vA.w - lg;
        oB.x = vB.x - lg; oB.y = vB.y - lg; oB.z = vB.z - lg; oB.w = vB.w - lg;
        ((float4*)(out + (size_t)node * OUT_C))[2 * sub]     = oA;
        ((float4*)(out + (size_t)node * OUT_C))[2 * sub + 1] = oB;
    }
}

// ---------------------------------------------------------------------------
// Launch
// ---------------------------------------------------------------------------
extern "C" void kernel_launch(void* const* d_in, const int* in_sizes, int n_in,
                              void* d_out, int out_size, void* d_ws, size_t ws_size,
                              hipStream_t stream) {
    const float* x  = (const float*)d_in[0];
    const int*   ei = (const int*)d_in[1];
    const float* w  = (const float*)d_in[2];
    const float* W1 = (const float*)d_in[3];
    const float* b1 = (const float*)d_in[4];
    const float* W2 = (const float*)d_in[5];
    const float* b2 = (const float*)d_in[6];
    const float* W3 = (const float*)d_in[7];
    const float* b3 = (const float*)d_in[8];
    float* out = (float*)d_out;

    char* ws = (char*)d_ws;
    size_t off = 0;
    auto carve = [&](size_t bytes) {
        char* p = ws + off;
        off += (bytes + 255) & ~(size_t)255;
        return p;
    };
    int*   bcursor = (int*)carve(NB * sizeof(int));
    uint*  rowinfo = (uint*)carve(N_NODES * sizeof(uint));
    float* dinv    = (float*)carve(N_NODES * sizeof(float));
    uint*  csr     = (uint*)carve(((size_t)NB * PBS + 64) * sizeof(uint));  // 11.0 MB
    uint2* tmp     = (uint2*)carve((size_t)NB * CAP * sizeof(uint2));       // 16.05 MB
    // tmp dead after k_build; reuse for bf16 activations
    ushort* g1 = (ushort*)tmp;                       // 6.4 MB
    ushort* g2 = g1 + (size_t)N_NODES * HID;         // 6.4 MB
    ushort* g3 = g1;                                 // g1 dead after layer-2 agg
    (void)ws_size;

    const int nbBin = (E_EDGES + TILE - 1) / TILE;   // 391
    const int nbN4  = N_NODES / 4;                   // 12500
    const int nbG1  = N_NODES / NPB;                 // 3125

    hipMemsetAsync(bcursor, 0, NB * sizeof(int), stream);
    k_bin<<<nbBin, P1T, 0, stream>>>(ei, w, bcursor, tmp);
    k_build<<<NB, BNODES, 0, stream>>>(bcursor, tmp, rowinfo, dinv, csr);

    k_gemm1<<<nbG1, 256, 0, stream>>>(x, W1, dinv, g1);
    k_agg_gemm<HID><<<nbN4, 256, 0, stream>>>(rowinfo, csr, g1, dinv, b1, W2, g2);
    k_agg_gemm<OUT_C><<<nbN4, 256, 0, stream>>>(rowinfo, csr, g2, dinv, b2, W3, g3);
    k_final_agg<<<nbN4, 256, 0, stream>>>(rowinfo, csr, g3, dinv, b3, out);
}

// Round 7
// 240.585 us; speedup vs baseline: 4.9926x; 1.0082x over previous
//
#include <hip/hip_runtime.h>
#include <math.h>

#define N_NODES 50000
#define E_EDGES 1600000
#define IN_C    128
#define HID     64
#define OUT_C   40

#define BSH     9            // nodes-per-bucket shift
#define BNODES  512          // 1 << BSH
#define NB      98           // ceil(50000/512)
#define CAP     20480        // tmp entries per bucket
#define PBS     28160        // padded csr stride per bucket
#define TILE    4096         // edges per block in binning pass
#define P1T     512
#define NPB     16           // nodes per block in gemm1

typedef unsigned int uint;
typedef unsigned short ushort;

__device__ inline float b2f(ushort h) { return __uint_as_float(((uint)h) << 16); }
__device__ inline ushort f2b(float f) {
    uint u = __float_as_uint(f);
    u += 0x7FFFu + ((u >> 16) & 1u);        // round-to-nearest-even
    return (ushort)(u >> 16);
}

// ---------------------------------------------------------------------------
// Pass 1: bin edges by dst bucket (LDS grouping, coalesced run-writes).
// ---------------------------------------------------------------------------
__global__ __launch_bounds__(P1T) void k_bin(const int* __restrict__ ei,
                                             const float* __restrict__ w,
                                             int* __restrict__ bcursor,
                                             uint2* __restrict__ tmp) {
    __shared__ uint2 stage[TILE];             // 32 KB
    __shared__ unsigned char sbuck[TILE];     // 4 KB
    __shared__ int hist[NB], startb[NB], cursor[NB], baseg[NB];
    __shared__ int sc[128];
    const int tid = threadIdx.x;
    const int e0  = blockIdx.x * TILE;
    const int n   = min(TILE, E_EDGES - e0);

    for (int i = tid; i < NB; i += P1T) hist[i] = 0;
    __syncthreads();

    for (int i = tid; i < n; i += P1T) {
        int d = ei[E_EDGES + e0 + i];
        atomicAdd(&hist[d >> BSH], 1);
    }
    __syncthreads();

    if (tid < 128) sc[tid] = (tid < NB) ? hist[tid] : 0;
    __syncthreads();
    for (int off = 1; off < 128; off <<= 1) {
        int x = 0;
        if (tid < 128 && tid >= off) x = sc[tid - off];
        __syncthreads();
        if (tid < 128) sc[tid] += x;
        __syncthreads();
    }
    if (tid < NB) {
        int st = sc[tid] - hist[tid];
        startb[tid] = st;
        cursor[tid] = st;
        baseg[tid]  = atomicAdd(&bcursor[tid], hist[tid]);   // reserve global run
    }
    __syncthreads();

    for (int i = tid; i < n; i += P1T) {
        int   s  = ei[e0 + i];
        int   d  = ei[E_EDGES + e0 + i];
        float wv = w[e0 + i];
        int   b  = d >> BSH;
        int pos = atomicAdd(&cursor[b], 1);
        stage[pos] = make_uint2(((uint)(d & (BNODES - 1)) << 16) | (uint)s,
                                __float_as_uint(wv));
        sbuck[pos] = (unsigned char)b;
    }
    __syncthreads();

    for (int i = tid; i < n; i += P1T) {
        int b = sbuck[i];
        int gpos = baseg[b] + (i - startb[b]);
        tmp[(size_t)b * CAP + gpos] = stage[i];
    }
}

// ---------------------------------------------------------------------------
// Pass 2: per-bucket CSR finalize, 16-padded rows.
// csr entry: (bf16(w)<<16) | src ; pads are 0. rowinfo=(n16<<24)|start.
// ---------------------------------------------------------------------------
__global__ __launch_bounds__(BNODES) void k_build(const int* __restrict__ bcursor,
                                                  const uint2* __restrict__ tmp,
                                                  uint* __restrict__ rowinfo,
                                                  float* __restrict__ dinv,
                                                  uint* __restrict__ csr) {
    __shared__ int   hist[BNODES];
    __shared__ float wsum[BNODES];
    __shared__ int   sc[BNODES];
    __shared__ int   cur[BNODES];
    const int tid = threadIdx.x;
    const int b   = blockIdx.x;
    const int cnt = bcursor[b];
    const uint2* tb = tmp + (size_t)b * CAP;

    hist[tid] = 0; wsum[tid] = 0.0f;
    __syncthreads();
    for (int i = tid; i < cnt; i += BNODES) {
        uint2 u = tb[i];
        int dl = u.x >> 16;
        atomicAdd(&hist[dl], 1);
        atomicAdd(&wsum[dl], __uint_as_float(u.y));
    }
    __syncthreads();

    const int deg  = hist[tid];
    const int pdeg = (deg + 15) & ~15;
    sc[tid] = pdeg;
    __syncthreads();
    for (int off = 1; off < BNODES; off <<= 1) {
        int x = (tid >= off) ? sc[tid - off] : 0;
        __syncthreads();
        sc[tid] += x;
        __syncthreads();
    }
    const int base = b * PBS + (sc[tid] - pdeg);   // 16-aligned row start
    const int node = (b << BSH) + tid;
    if (node < N_NODES) {
        rowinfo[node] = ((uint)(pdeg >> 4) << 24) | (uint)base;
        dinv[node]    = rsqrtf(1.0f + wsum[tid]);
    }
    cur[tid] = base;
    __syncthreads();

    for (int i = tid; i < cnt; i += BNODES) {
        uint2 u = tb[i];
        int dl = u.x >> 16;
        int pos = atomicAdd(&cur[dl], 1);
        csr[pos] = ((uint)f2b(__uint_as_float(u.y)) << 16) | (u.x & 0xFFFFu);
    }
    for (int i = deg; i < pdeg; ++i) csr[base + i] = 0u;   // zero-weight pads
}

// ---------------------------------------------------------------------------
// Layer-1 GEMM: g1 = bf16( dinv[i] * (x[i] @ W1) ). W1 + 16 x-rows in LDS.
// ---------------------------------------------------------------------------
__global__ __launch_bounds__(256) void k_gemm1(const float* __restrict__ x,
                                               const float* __restrict__ W,
                                               const float* __restrict__ dinv,
                                               ushort* __restrict__ g) {
    __shared__ float sW[IN_C * HID];      // 32 KB
    __shared__ float sx[NPB * IN_C];      // 8 KB
    const int tid = threadIdx.x;
    const size_t base = (size_t)blockIdx.x * NPB;

    for (int i = tid; i < (IN_C * HID) / 4; i += 256)
        ((float4*)sW)[i] = ((const float4*)W)[i];
    for (int i = tid; i < (NPB * IN_C) / 4; i += 256)
        ((float4*)sx)[i] = ((const float4*)(x + base * IN_C))[i];
    __syncthreads();

    const int wv = tid >> 6, f = tid & 63;
    for (int nn = 0; nn < 4; ++nn) {
        const int nl = wv * 4 + nn;
        const float* row = &sx[nl * IN_C];
        float acc = 0.0f;
#pragma unroll 8
        for (int k = 0; k < IN_C; k += 4) {
            float4 a = *(const float4*)&row[k];
            acc += a.x * sW[(k + 0) * HID + f] + a.y * sW[(k + 1) * HID + f]
                 + a.z * sW[(k + 2) * HID + f] + a.w * sW[(k + 3) * HID + f];
        }
        const size_t node = base + nl;
        g[node * HID + f] = f2b(dinv[node] * acc);
    }
}

// ---------------------------------------------------------------------------
// Fused: aggregate + relu(dinv*agg+b) + GEMM (LDS W).
// LANE = FEATURE. One wave per node. Descriptors -> SGPR via readlane:
// weight is an SGPR fmac operand, gather addr = SGPR base + lane*2.
// 16 independent 128B gathers batched per block -> deep vmcnt pipeline.
// ---------------------------------------------------------------------------
template <int F_OUT>
__global__ __launch_bounds__(256) void k_agg_gemm(const uint* __restrict__ rowinfo,
                                                  const uint* __restrict__ csr,
                                                  const ushort* __restrict__ g,
                                                  const float* __restrict__ dinv,
                                                  const float* __restrict__ bias,
                                                  const float* __restrict__ W,
                                                  ushort* __restrict__ g_next) {
    __shared__ float sW[HID * F_OUT];
    __shared__ float s_act[4][HID];
    const int tid = threadIdx.x;
    for (int i = tid; i < HID * F_OUT; i += 256) sW[i] = W[i];   // sync deferred

    const int wv = tid >> 6, lane = tid & 63;
    const int node = blockIdx.x * 4 + wv;
    const uint ri  = rowinfo[node];
    const int  n16 = (int)(ri >> 24);
    const float dv = dinv[node];

    float acc0 = b2f(g[(size_t)node * HID + lane]);   // self loop (w=1)
    float acc1 = 0.0f;

    const uint* rp = csr + (ri & 0xFFFFFFu);
    uint d = rp[lane & 15];
    for (int blk = 0; blk < n16; ++blk) {
        uint dn = rp[((blk + 1) << 4) + (lane & 15)];   // prefetch (slack-covered)
        ushort uv[16];
        uint   sw[16];
#pragma unroll
        for (int j = 0; j < 16; ++j) {
            uint dj = (uint)__builtin_amdgcn_readlane((int)d, j);
            sw[j] = dj & 0xFFFF0000u;
            uv[j] = g[(size_t)(dj & 0xFFFFu) * HID + lane];
        }
#pragma unroll
        for (int j = 0; j < 16; ++j) {
            float f = b2f(uv[j]);
            if (j & 1) acc1 += __uint_as_float(sw[j]) * f;
            else       acc0 += __uint_as_float(sw[j]) * f;
        }
        d = dn;
    }
    float acc = acc0 + acc1;

    s_act[wv][lane] = fmaxf(dv * acc + bias[lane], 0.0f);
    __syncthreads();
    if (lane < F_OUT) {
        float dot = 0.0f;
#pragma unroll 4
        for (int k = 0; k < HID; k += 4) {
            float4 a = *(const float4*)&s_act[wv][k];
            dot += a.x * sW[(k + 0) * F_OUT + lane] + a.y * sW[(k + 1) * F_OUT + lane]
                 + a.z * sW[(k + 2) * F_OUT + lane] + a.w * sW[(k + 3) * F_OUT + lane];
        }
        g_next[(size_t)node * F_OUT + lane] = f2b(dinv[node] * dot);
    }
}

// ---------------------------------------------------------------------------
// Final: aggregate (width 40, lanes 40..63 dead) + relu + log_softmax -> out
// ---------------------------------------------------------------------------
__global__ __launch_bounds__(256) void k_final_agg(const uint* __restrict__ rowinfo,
                                                   const uint* __restrict__ csr,
                                                   const ushort* __restrict__ g,
                                                   const float* __restrict__ dinv,
                                                   const float* __restrict__ bias,
                                                   float* __restrict__ out) {
    const int tid = threadIdx.x;
    const int wv = tid >> 6, lane = tid & 63;
    const int node = blockIdx.x * 4 + wv;
    const bool live = lane < OUT_C;
    const uint ri  = rowinfo[node];
    const int  n16 = (int)(ri >> 24);
    const float dv = dinv[node];

    float acc0 = live ? b2f(g[(size_t)node * OUT_C + lane]) : 0.0f;  // self loop
    float acc1 = 0.0f;

    const uint* rp = csr + (ri & 0xFFFFFFu);
    uint d = rp[lane & 15];
    for (int blk = 0; blk < n16; ++blk) {
        uint dn = rp[((blk + 1) << 4) + (lane & 15)];
        ushort uv[16];
        uint   sw[16];
#pragma unroll
        for (int j = 0; j < 16; ++j) {
            uint dj = (uint)__builtin_amdgcn_readlane((int)d, j);
            sw[j] = dj & 0xFFFF0000u;
            uv[j] = g[(size_t)(dj & 0xFFFFu) * OUT_C + lane];   // over-read ok (slack)
        }
#pragma unroll
        for (int j = 0; j < 16; ++j) {
            float f = b2f(uv[j]);
            if (j & 1) acc1 += __uint_as_float(sw[j]) * f;
            else       acc0 += __uint_as_float(sw[j]) * f;
        }
        d = dn;
    }
    float acc = acc0 + acc1;

    float bl = live ? bias[lane] : 0.0f;
    float v  = live ? fmaxf(dv * acc + bl, 0.0f) : -INFINITY;
    float mx = v;
#pragma unroll
    for (int off = 32; off > 0; off >>= 1) mx = fmaxf(mx, __shfl_xor(mx, off));
    float ex = live ? expf(v - mx) : 0.0f;
    float se = ex;
#pragma unroll
    for (int off = 32; off > 0; off >>= 1) se += __shfl_xor(se, off);
    if (live) out[(size_t)node * OUT_C + lane] = v - mx - logf(se);
}

// ---------------------------------------------------------------------------
// Launch
// ---------------------------------------------------------------------------
extern "C" void kernel_launch(void* const* d_in, const int* in_sizes, int n_in,
                              void* d_out, int out_size, void* d_ws, size_t ws_size,
                              hipStream_t stream) {
    const float* x  = (const float*)d_in[0];
    const int*   ei = (const int*)d_in[1];
    const float* w  = (const float*)d_in[2];
    const float* W1 = (const float*)d_in[3];
    const float* b1 = (const float*)d_in[4];
    const float* W2 = (const float*)d_in[5];
    const float* b2 = (const float*)d_in[6];
    const float* W3 = (const float*)d_in[7];
    const float* b3 = (const float*)d_in[8];
    float* out = (float*)d_out;

    char* ws = (char*)d_ws;
    size_t off = 0;
    auto carve = [&](size_t bytes) {
        char* p = ws + off;
        off += (bytes + 255) & ~(size_t)255;
        return p;
    };
    int*   bcursor = (int*)carve(NB * sizeof(int));
    uint*  rowinfo = (uint*)carve(N_NODES * sizeof(uint));
    float* dinv    = (float*)carve(N_NODES * sizeof(float));
    uint*  csr     = (uint*)carve(((size_t)NB * PBS + 64) * sizeof(uint));  // 11.0 MB
    uint2* tmp     = (uint2*)carve((size_t)NB * CAP * sizeof(uint2) + 256); // 16.05 MB
    // tmp dead after k_build; reuse for bf16 activations (slack for over-reads)
    ushort* g1 = (ushort*)tmp;                       // 6.4 MB
    ushort* g2 = g1 + (size_t)N_NODES * HID;         // 6.4 MB
    ushort* g3 = g1;                                 // g1 dead after layer-2 agg
    (void)ws_size;

    const int nbBin = (E_EDGES + TILE - 1) / TILE;   // 391
    const int nbN4  = N_NODES / 4;                   // 12500
    const int nbG1  = N_NODES / NPB;                 // 3125

    hipMemsetAsync(bcursor, 0, NB * sizeof(int), stream);
    k_bin<<<nbBin, P1T, 0, stream>>>(ei, w, bcursor, tmp);
    k_build<<<NB, BNODES, 0, stream>>>(bcursor, tmp, rowinfo, dinv, csr);

    k_gemm1<<<nbG1, 256, 0, stream>>>(x, W1, dinv, g1);
    k_agg_gemm<HID><<<nbN4, 256, 0, stream>>>(rowinfo, csr, g1, dinv, b1, W2, g2);
    k_agg_gemm<OUT_C><<<nbN4, 256, 0, stream>>>(rowinfo, csr, g2, dinv, b2, W3, g3);
    k_final_agg<<<nbN4, 256, 0, stream>>>(rowinfo, csr, g3, dinv, b3, out);
}

// Round 8
// 229.111 us; speedup vs baseline: 5.2427x; 1.0501x over previous
//
#include <hip/hip_runtime.h>
#include <hip/hip_fp8.h>
#include <math.h>

#define N_NODES 50000
#define E_EDGES 1600000
#define IN_C    128
#define HID     64
#define OUT_C   40

#define BSH     9            // nodes-per-bucket shift
#define BNODES  512          // 1 << BSH
#define NB      98           // ceil(50000/512)
#define CAP     20480        // tmp entries per bucket
#define PBS     28160        // padded csr stride per bucket
#define TILE    4096         // edges per block in binning pass
#define P1T     512
#define NPB     16           // nodes per block in gemm1

typedef unsigned int uint;
typedef unsigned short ushort;
typedef unsigned char uchar;

__device__ inline ushort f2b(float f) {
    uint u = __float_as_uint(f);
    u += 0x7FFFu + ((u >> 16) & 1u);        // round-to-nearest-even
    return (ushort)(u >> 16);
}
__device__ inline float b2f(ushort h) { return __uint_as_float(((uint)h) << 16); }

// fp8 e4m3 (OCP, gfx950 HW converts)
__device__ inline uint ftof8(float f) { __hip_fp8_e4m3 t(f); return (uint)t.__x; }
__device__ inline float f8tof(uint b) { return __builtin_amdgcn_cvt_f32_fp8(b, 0); }

// ---------------------------------------------------------------------------
// Pass 1: bin edges by dst bucket (LDS grouping, coalesced run-writes).
// ---------------------------------------------------------------------------
__global__ __launch_bounds__(P1T) void k_bin(const int* __restrict__ ei,
                                             const float* __restrict__ w,
                                             int* __restrict__ bcursor,
                                             uint2* __restrict__ tmp) {
    __shared__ uint2 stage[TILE];             // 32 KB
    __shared__ unsigned char sbuck[TILE];     // 4 KB
    __shared__ int hist[NB], startb[NB], cursor[NB], baseg[NB];
    __shared__ int sc[128];
    const int tid = threadIdx.x;
    const int e0  = blockIdx.x * TILE;
    const int n   = min(TILE, E_EDGES - e0);

    for (int i = tid; i < NB; i += P1T) hist[i] = 0;
    __syncthreads();

    for (int i = tid; i < n; i += P1T) {
        int d = ei[E_EDGES + e0 + i];
        atomicAdd(&hist[d >> BSH], 1);
    }
    __syncthreads();

    if (tid < 128) sc[tid] = (tid < NB) ? hist[tid] : 0;
    __syncthreads();
    for (int off = 1; off < 128; off <<= 1) {
        int x = 0;
        if (tid < 128 && tid >= off) x = sc[tid - off];
        __syncthreads();
        if (tid < 128) sc[tid] += x;
        __syncthreads();
    }
    if (tid < NB) {
        int st = sc[tid] - hist[tid];
        startb[tid] = st;
        cursor[tid] = st;
        baseg[tid]  = atomicAdd(&bcursor[tid], hist[tid]);   // reserve global run
    }
    __syncthreads();

    for (int i = tid; i < n; i += P1T) {
        int   s  = ei[e0 + i];
        int   d  = ei[E_EDGES + e0 + i];
        float wv = w[e0 + i];
        int   b  = d >> BSH;
        int pos = atomicAdd(&cursor[b], 1);
        stage[pos] = make_uint2(((uint)(d & (BNODES - 1)) << 16) | (uint)s,
                                __float_as_uint(wv));
        sbuck[pos] = (unsigned char)b;
    }
    __syncthreads();

    for (int i = tid; i < n; i += P1T) {
        int b = sbuck[i];
        int gpos = baseg[b] + (i - startb[b]);
        tmp[(size_t)b * CAP + gpos] = stage[i];
    }
}

// ---------------------------------------------------------------------------
// Pass 2: per-bucket CSR finalize, 16-padded rows.
// csr entry: (bf16(w)<<16) | src ; pads are 0. rowinfo=(n16<<24)|start.
// ---------------------------------------------------------------------------
__global__ __launch_bounds__(BNODES) void k_build(const int* __restrict__ bcursor,
                                                  const uint2* __restrict__ tmp,
                                                  uint* __restrict__ rowinfo,
                                                  float* __restrict__ dinv,
                                                  uint* __restrict__ csr) {
    __shared__ int   hist[BNODES];
    __shared__ float wsum[BNODES];
    __shared__ int   sc[BNODES];
    __shared__ int   cur[BNODES];
    const int tid = threadIdx.x;
    const int b   = blockIdx.x;
    const int cnt = bcursor[b];
    const uint2* tb = tmp + (size_t)b * CAP;

    hist[tid] = 0; wsum[tid] = 0.0f;
    __syncthreads();
    for (int i = tid; i < cnt; i += BNODES) {
        uint2 u = tb[i];
        int dl = u.x >> 16;
        atomicAdd(&hist[dl], 1);
        atomicAdd(&wsum[dl], __uint_as_float(u.y));
    }
    __syncthreads();

    const int deg  = hist[tid];
    const int pdeg = (deg + 15) & ~15;
    sc[tid] = pdeg;
    __syncthreads();
    for (int off = 1; off < BNODES; off <<= 1) {
        int x = (tid >= off) ? sc[tid - off] : 0;
        __syncthreads();
        sc[tid] += x;
        __syncthreads();
    }
    const int base = b * PBS + (sc[tid] - pdeg);   // 16-aligned row start
    const int node = (b << BSH) + tid;
    if (node < N_NODES) {
        rowinfo[node] = ((uint)(pdeg >> 4) << 24) | (uint)base;
        dinv[node]    = rsqrtf(1.0f + wsum[tid]);
    }
    cur[tid] = base;
    __syncthreads();

    for (int i = tid; i < cnt; i += BNODES) {
        uint2 u = tb[i];
        int dl = u.x >> 16;
        int pos = atomicAdd(&cur[dl], 1);
        csr[pos] = ((uint)f2b(__uint_as_float(u.y)) << 16) | (u.x & 0xFFFFu);
    }
    for (int i = deg; i < pdeg; ++i) csr[base + i] = 0u;   // zero-weight pads
}

// ---------------------------------------------------------------------------
// Layer-1 GEMM: g1 = fp8( dinv[i] * (x[i] @ W1) ). W1 + 16 x-rows in LDS.
// ---------------------------------------------------------------------------
__global__ __launch_bounds__(256) void k_gemm1(const float* __restrict__ x,
                                               const float* __restrict__ W,
                                               const float* __restrict__ dinv,
                                               uchar* __restrict__ g) {
    __shared__ float sW[IN_C * HID];      // 32 KB
    __shared__ float sx[NPB * IN_C];      // 8 KB
    const int tid = threadIdx.x;
    const size_t base = (size_t)blockIdx.x * NPB;

    for (int i = tid; i < (IN_C * HID) / 4; i += 256)
        ((float4*)sW)[i] = ((const float4*)W)[i];
    for (int i = tid; i < (NPB * IN_C) / 4; i += 256)
        ((float4*)sx)[i] = ((const float4*)(x + base * IN_C))[i];
    __syncthreads();

    const int wv = tid >> 6, f = tid & 63;
    for (int nn = 0; nn < 4; ++nn) {
        const int nl = wv * 4 + nn;
        const float* row = &sx[nl * IN_C];
        float acc = 0.0f;
#pragma unroll 8
        for (int k = 0; k < IN_C; k += 4) {
            float4 a = *(const float4*)&row[k];
            acc += a.x * sW[(k + 0) * HID + f] + a.y * sW[(k + 1) * HID + f]
                 + a.z * sW[(k + 2) * HID + f] + a.w * sW[(k + 3) * HID + f];
        }
        const size_t node = base + nl;
        g[node * HID + f] = (uchar)ftof8(dinv[node] * acc);
    }
}

// ---------------------------------------------------------------------------
// Fused: aggregate (fp8 gather) + relu(dinv*agg+b) + GEMM (LDS W).
// LANE = FEATURE, fp8 rows (64B = one wave request). Descriptors -> SGPR via
// readlane: weight SGPR, gather addr = SGPR base + lane. 16 loads/block.
// ---------------------------------------------------------------------------
template <int F_OUT>
__global__ __launch_bounds__(256) void k_agg_gemm(const uint* __restrict__ rowinfo,
                                                  const uint* __restrict__ csr,
                                                  const uchar* __restrict__ g,
                                                  const float* __restrict__ dinv,
                                                  const float* __restrict__ bias,
                                                  const float* __restrict__ W,
                                                  uchar* __restrict__ g_next) {
    __shared__ float sW[HID * F_OUT];
    __shared__ float s_act[4][HID];
    const int tid = threadIdx.x;
    for (int i = tid; i < HID * F_OUT; i += 256) sW[i] = W[i];   // sync deferred

    const int wv = tid >> 6, lane = tid & 63;
    const int node = blockIdx.x * 4 + wv;
    const uint ri  = rowinfo[node];
    const int  n16 = (int)(ri >> 24);
    const float dv = dinv[node];

    float acc0 = f8tof(g[(size_t)node * HID + lane]);   // self loop (w=1)
    float acc1 = 0.0f;

    const uint* rp = csr + (ri & 0xFFFFFFu);
    uint d = rp[lane & 15];
    for (int blk = 0; blk < n16; ++blk) {
        uint dn = rp[((blk + 1) << 4) + (lane & 15)];   // prefetch (slack-covered)
        uchar uv[16];
        uint  sw[16];
#pragma unroll
        for (int j = 0; j < 16; ++j) {
            uint dj = (uint)__builtin_amdgcn_readlane((int)d, j);
            sw[j] = dj & 0xFFFF0000u;
            uv[j] = g[(size_t)(dj & 0xFFFFu) * HID + lane];
        }
#pragma unroll
        for (int j = 0; j < 16; ++j) {
            float f = f8tof((uint)uv[j]);
            if (j & 1) acc1 += __uint_as_float(sw[j]) * f;
            else       acc0 += __uint_as_float(sw[j]) * f;
        }
        d = dn;
    }
    float acc = acc0 + acc1;

    s_act[wv][lane] = fmaxf(dv * acc + bias[lane], 0.0f);
    __syncthreads();
    if (lane < F_OUT) {
        float dot = 0.0f;
#pragma unroll 4
        for (int k = 0; k < HID; k += 4) {
            float4 a = *(const float4*)&s_act[wv][k];
            dot += a.x * sW[(k + 0) * F_OUT + lane] + a.y * sW[(k + 1) * F_OUT + lane]
                 + a.z * sW[(k + 2) * F_OUT + lane] + a.w * sW[(k + 3) * F_OUT + lane];
        }
        g_next[(size_t)node * F_OUT + lane] = (uchar)ftof8(dinv[node] * dot);
    }
}

// ---------------------------------------------------------------------------
// Final: aggregate (fp8, width 40, lanes 40..63 dead) + relu + log_softmax
// ---------------------------------------------------------------------------
__global__ __launch_bounds__(256) void k_final_agg(const uint* __restrict__ rowinfo,
                                                   const uint* __restrict__ csr,
                                                   const uchar* __restrict__ g,
                                                   const float* __restrict__ dinv,
                                                   const float* __restrict__ bias,
                                                   float* __restrict__ out) {
    const int tid = threadIdx.x;
    const int wv = tid >> 6, lane = tid & 63;
    const int node = blockIdx.x * 4 + wv;
    const bool live = lane < OUT_C;
    const uint ri  = rowinfo[node];
    const int  n16 = (int)(ri >> 24);
    const float dv = dinv[node];

    float acc0 = live ? f8tof(g[(size_t)node * OUT_C + lane]) : 0.0f;  // self loop
    float acc1 = 0.0f;

    const uint* rp = csr + (ri & 0xFFFFFFu);
    uint d = rp[lane & 15];
    for (int blk = 0; blk < n16; ++blk) {
        uint dn = rp[((blk + 1) << 4) + (lane & 15)];
        uchar uv[16];
        uint  sw[16];
#pragma unroll
        for (int j = 0; j < 16; ++j) {
            uint dj = (uint)__builtin_amdgcn_readlane((int)d, j);
            sw[j] = dj & 0xFFFF0000u;
            uv[j] = g[(size_t)(dj & 0xFFFFu) * OUT_C + lane];   // over-read ok (slack)
        }
#pragma unroll
        for (int j = 0; j < 16; ++j) {
            float f = f8tof((uint)uv[j]);
            if (j & 1) acc1 += __uint_as_float(sw[j]) * f;
            else       acc0 += __uint_as_float(sw[j]) * f;
        }
        d = dn;
    }
    float acc = acc0 + acc1;

    float bl = live ? bias[lane] : 0.0f;
    float v  = live ? fmaxf(dv * acc + bl, 0.0f) : -INFINITY;
    float mx = v;
#pragma unroll
    for (int off = 32; off > 0; off >>= 1) mx = fmaxf(mx, __shfl_xor(mx, off));
    float ex = live ? expf(v - mx) : 0.0f;
    float se = ex;
#pragma unroll
    for (int off = 32; off > 0; off >>= 1) se += __shfl_xor(se, off);
    if (live) out[(size_t)node * OUT_C + lane] = v - mx - logf(se);
}

// ---------------------------------------------------------------------------
// Launch
// ---------------------------------------------------------------------------
extern "C" void kernel_launch(void* const* d_in, const int* in_sizes, int n_in,
                              void* d_out, int out_size, void* d_ws, size_t ws_size,
                              hipStream_t stream) {
    const float* x  = (const float*)d_in[0];
    const int*   ei = (const int*)d_in[1];
    const float* w  = (const float*)d_in[2];
    const float* W1 = (const float*)d_in[3];
    const float* b1 = (const float*)d_in[4];
    const float* W2 = (const float*)d_in[5];
    const float* b2 = (const float*)d_in[6];
    const float* W3 = (const float*)d_in[7];
    const float* b3 = (const float*)d_in[8];
    float* out = (float*)d_out;

    char* ws = (char*)d_ws;
    size_t off = 0;
    auto carve = [&](size_t bytes) {
        char* p = ws + off;
        off += (bytes + 255) & ~(size_t)255;
        return p;
    };
    int*   bcursor = (int*)carve(NB * sizeof(int));
    uint*  rowinfo = (uint*)carve(N_NODES * sizeof(uint));
    float* dinv    = (float*)carve(N_NODES * sizeof(float));
    uint*  csr     = (uint*)carve(((size_t)NB * PBS + 64) * sizeof(uint));  // 11.0 MB
    uint2* tmp     = (uint2*)carve((size_t)NB * CAP * sizeof(uint2) + 256); // 16.05 MB
    // tmp dead after k_build; reuse for fp8 activations (slack for over-reads)
    uchar* g1 = (uchar*)tmp;                         // 3.2 MB
    uchar* g2 = g1 + (size_t)N_NODES * HID;          // 3.2 MB
    uchar* g3 = g1;                                  // 2 MB; g1 dead after layer-2 agg
    (void)ws_size;

    const int nbBin = (E_EDGES + TILE - 1) / TILE;   // 391
    const int nbN4  = N_NODES / 4;                   // 12500
    const int nbG1  = N_NODES / NPB;                 // 3125

    hipMemsetAsync(bcursor, 0, NB * sizeof(int), stream);
    k_bin<<<nbBin, P1T, 0, stream>>>(ei, w, bcursor, tmp);
    k_build<<<NB, BNODES, 0, stream>>>(bcursor, tmp, rowinfo, dinv, csr);

    k_gemm1<<<nbG1, 256, 0, stream>>>(x, W1, dinv, g1);
    k_agg_gemm<HID><<<nbN4, 256, 0, stream>>>(rowinfo, csr, g1, dinv, b1, W2, g2);
    k_agg_gemm<OUT_C><<<nbN4, 256, 0, stream>>>(rowinfo, csr, g2, dinv, b2, W3, g3);
    k_final_agg<<<nbN4, 256, 0, stream>>>(rowinfo, csr, g3, dinv, b3, out);
}

// Round 10
// 227.325 us; speedup vs baseline: 5.2839x; 1.0079x over previous
//
#include <hip/hip_runtime.h>
#include <hip/hip_fp8.h>
#include <math.h>

#define N_NODES 50000
#define E_EDGES 1600000
#define IN_C    128
#define HID     64
#define OUT_C   40

#define BSH     9            // nodes-per-bucket shift
#define BNODES  512          // 1 << BSH
#define NB      98           // ceil(50000/512)
#define CAP     20480        // tmp entries per bucket
#define PBS     28160        // padded csr stride per bucket
#define TILE    4096         // edges per block in binning pass
#define P1T     512
#define NPB     16           // nodes per block in gemm1

typedef unsigned int uint;
typedef unsigned short ushort;
typedef unsigned char uchar;

__device__ inline ushort f2b(float f) {
    uint u = __float_as_uint(f);
    u += 0x7FFFu + ((u >> 16) & 1u);        // round-to-nearest-even
    return (ushort)(u >> 16);
}
// fp8 e4m3 (OCP, gfx950 HW converts). Byte-select must be a literal constant.
__device__ inline uint ftof8(float f) { __hip_fp8_e4m3 t(f); return (uint)t.__x; }
template <int SEL>
__device__ __forceinline__ float f8v(uint dw) {
    return __builtin_amdgcn_cvt_f32_fp8(dw, SEL);
}

// ---------------------------------------------------------------------------
// Pass 1: bin edges by dst bucket (LDS grouping, coalesced run-writes).
// ---------------------------------------------------------------------------
__global__ __launch_bounds__(P1T) void k_bin(const int* __restrict__ ei,
                                             const float* __restrict__ w,
                                             int* __restrict__ bcursor,
                                             uint2* __restrict__ tmp) {
    __shared__ uint2 stage[TILE];             // 32 KB
    __shared__ unsigned char sbuck[TILE];     // 4 KB
    __shared__ int hist[NB], startb[NB], cursor[NB], baseg[NB];
    __shared__ int sc[128];
    const int tid = threadIdx.x;
    const int e0  = blockIdx.x * TILE;
    const int n   = min(TILE, E_EDGES - e0);

    for (int i = tid; i < NB; i += P1T) hist[i] = 0;
    __syncthreads();

    for (int i = tid; i < n; i += P1T) {
        int d = ei[E_EDGES + e0 + i];
        atomicAdd(&hist[d >> BSH], 1);
    }
    __syncthreads();

    if (tid < 128) sc[tid] = (tid < NB) ? hist[tid] : 0;
    __syncthreads();
    for (int off = 1; off < 128; off <<= 1) {
        int x = 0;
        if (tid < 128 && tid >= off) x = sc[tid - off];
        __syncthreads();
        if (tid < 128) sc[tid] += x;
        __syncthreads();
    }
    if (tid < NB) {
        int st = sc[tid] - hist[tid];
        startb[tid] = st;
        cursor[tid] = st;
        baseg[tid]  = atomicAdd(&bcursor[tid], hist[tid]);   // reserve global run
    }
    __syncthreads();

    for (int i = tid; i < n; i += P1T) {
        int   s  = ei[e0 + i];
        int   d  = ei[E_EDGES + e0 + i];
        float wv = w[e0 + i];
        int   b  = d >> BSH;
        int pos = atomicAdd(&cursor[b], 1);
        stage[pos] = make_uint2(((uint)(d & (BNODES - 1)) << 16) | (uint)s,
                                __float_as_uint(wv));
        sbuck[pos] = (unsigned char)b;
    }
    __syncthreads();

    for (int i = tid; i < n; i += P1T) {
        int b = sbuck[i];
        int gpos = baseg[b] + (i - startb[b]);
        tmp[(size_t)b * CAP + gpos] = stage[i];
    }
}

// ---------------------------------------------------------------------------
// Pass 2: per-bucket CSR finalize, 16-padded rows.
// csr entry: (bf16(w)<<16) | src ; pads are 0. rowinfo=(n16<<24)|start.
// ---------------------------------------------------------------------------
__global__ __launch_bounds__(BNODES) void k_build(const int* __restrict__ bcursor,
                                                  const uint2* __restrict__ tmp,
                                                  uint* __restrict__ rowinfo,
                                                  float* __restrict__ dinv,
                                                  uint* __restrict__ csr) {
    __shared__ int   hist[BNODES];
    __shared__ float wsum[BNODES];
    __shared__ int   sc[BNODES];
    __shared__ int   cur[BNODES];
    const int tid = threadIdx.x;
    const int b   = blockIdx.x;
    const int cnt = bcursor[b];
    const uint2* tb = tmp + (size_t)b * CAP;

    hist[tid] = 0; wsum[tid] = 0.0f;
    __syncthreads();
    for (int i = tid; i < cnt; i += BNODES) {
        uint2 u = tb[i];
        int dl = u.x >> 16;
        atomicAdd(&hist[dl], 1);
        atomicAdd(&wsum[dl], __uint_as_float(u.y));
    }
    __syncthreads();

    const int deg  = hist[tid];
    const int pdeg = (deg + 15) & ~15;
    sc[tid] = pdeg;
    __syncthreads();
    for (int off = 1; off < BNODES; off <<= 1) {
        int x = (tid >= off) ? sc[tid - off] : 0;
        __syncthreads();
        sc[tid] += x;
        __syncthreads();
    }
    const int base = b * PBS + (sc[tid] - pdeg);   // 16-aligned row start
    const int node = (b << BSH) + tid;
    if (node < N_NODES) {
        rowinfo[node] = ((uint)(pdeg >> 4) << 24) | (uint)base;
        dinv[node]    = rsqrtf(1.0f + wsum[tid]);
    }
    cur[tid] = base;
    __syncthreads();

    for (int i = tid; i < cnt; i += BNODES) {
        uint2 u = tb[i];
        int dl = u.x >> 16;
        int pos = atomicAdd(&cur[dl], 1);
        csr[pos] = ((uint)f2b(__uint_as_float(u.y)) << 16) | (u.x & 0xFFFFu);
    }
    for (int i = deg; i < pdeg; ++i) csr[base + i] = 0u;   // zero-weight pads
}

// ---------------------------------------------------------------------------
// Layer-1 GEMM: g1 = fp8( dinv[i] * (x[i] @ W1) ). W1 + 16 x-rows in LDS.
// ---------------------------------------------------------------------------
__global__ __launch_bounds__(256) void k_gemm1(const float* __restrict__ x,
                                               const float* __restrict__ W,
                                               const float* __restrict__ dinv,
                                               uchar* __restrict__ g) {
    __shared__ float sW[IN_C * HID];      // 32 KB
    __shared__ float sx[NPB * IN_C];      // 8 KB
    const int tid = threadIdx.x;
    const size_t base = (size_t)blockIdx.x * NPB;

    for (int i = tid; i < (IN_C * HID) / 4; i += 256)
        ((float4*)sW)[i] = ((const float4*)W)[i];
    for (int i = tid; i < (NPB * IN_C) / 4; i += 256)
        ((float4*)sx)[i] = ((const float4*)(x + base * IN_C))[i];
    __syncthreads();

    const int wv = tid >> 6, f = tid & 63;
    for (int nn = 0; nn < 4; ++nn) {
        const int nl = wv * 4 + nn;
        const float* row = &sx[nl * IN_C];
        float acc = 0.0f;
#pragma unroll 8
        for (int k = 0; k < IN_C; k += 4) {
            float4 a = *(const float4*)&row[k];
            acc += a.x * sW[(k + 0) * HID + f] + a.y * sW[(k + 1) * HID + f]
                 + a.z * sW[(k + 2) * HID + f] + a.w * sW[(k + 3) * HID + f];
        }
        const size_t node = base + nl;
        g[node * HID + f] = (uchar)ftof8(dinv[node] * acc);
    }
}

// ---------------------------------------------------------------------------
// Shared inner loop: aggregate one 64-wide fp8 row per wave.
// grp = lane>>4 (edge slot), sub = lane&15 (dword = 4 fp8 feats).
// Per 4-edge subgroup: 1 shfl + 2 VALU addr + 1 dword load + 4 cvt + 4 fmac.
// After xor-reduce, ALL lanes hold feature quad [4*sub .. 4*sub+3].
// ---------------------------------------------------------------------------
__device__ __forceinline__ float4 agg_row64(const uint* __restrict__ csr,
                                            const uint* __restrict__ gw,
                                            uint ri, int node, int lane) {
    const int grp = lane >> 4, sub = lane & 15;
    const int n16 = (int)(ri >> 24);
    float4 acc = {0.f, 0.f, 0.f, 0.f};
    if (grp == 0) {                       // self loop, weight 1
        uint dw = gw[((uint)node << 4) + sub];
        acc.x = f8v<0>(dw); acc.y = f8v<1>(dw); acc.z = f8v<2>(dw); acc.w = f8v<3>(dw);
    }
    const uint* rp = csr + (ri & 0xFFFFFFu);
    uint d = rp[sub];                     // 16 descriptors per block
    for (int blk = 0; blk < n16; ++blk) {
        uint dn = rp[((blk + 1) << 4) + sub];   // prefetch (slack-covered)
#pragma unroll
        for (int i = 0; i < 4; ++i) {
            uint dj  = __shfl(d, 4 * i + grp);
            float wg = __uint_as_float(dj & 0xFFFF0000u);     // bf16 weight
            uint dw  = gw[((dj & 0xFFFFu) << 4) + sub];       // 4 fp8 feats
            acc.x += wg * f8v<0>(dw);
            acc.y += wg * f8v<1>(dw);
            acc.z += wg * f8v<2>(dw);
            acc.w += wg * f8v<3>(dw);
        }
        d = dn;
    }
#pragma unroll
    for (int m = 16; m <= 32; m <<= 1) {
        acc.x += __shfl_xor(acc.x, m); acc.y += __shfl_xor(acc.y, m);
        acc.z += __shfl_xor(acc.z, m); acc.w += __shfl_xor(acc.w, m);
    }
    return acc;
}

// ---------------------------------------------------------------------------
// A: aggregate g1 -> act1 = relu(dv*acc+b1) -> GEMM W2 -> g2 = fp8(dv*dot)
// ---------------------------------------------------------------------------
__global__ __launch_bounds__(256) void k_aggA(const uint* __restrict__ rowinfo,
                                              const uint* __restrict__ csr,
                                              const uint* __restrict__ gw,
                                              const float* __restrict__ dinv,
                                              const float* __restrict__ bias,
                                              const float* __restrict__ W,
                                              uchar* __restrict__ g_next) {
    __shared__ float sW[HID * HID];       // 16 KB
    __shared__ float s_act[4][HID];
    const int tid = threadIdx.x;
    for (int i = tid; i < HID * HID; i += 256) sW[i] = W[i];   // sync deferred

    const int wv = tid >> 6, lane = tid & 63;
    const int node = blockIdx.x * 4 + wv;
    const uint ri  = rowinfo[node];
    const float dv = dinv[node];

    float4 acc = agg_row64(csr, gw, ri, node, lane);

    if ((lane >> 4) == 0) {
        const int sub = lane & 15;
        float4 b4 = ((const float4*)bias)[sub];
        float4 r;
        r.x = fmaxf(dv * acc.x + b4.x, 0.f);
        r.y = fmaxf(dv * acc.y + b4.y, 0.f);
        r.z = fmaxf(dv * acc.z + b4.z, 0.f);
        r.w = fmaxf(dv * acc.w + b4.w, 0.f);
        ((float4*)&s_act[wv][0])[sub] = r;
    }
    __syncthreads();
    float dot = 0.0f;
#pragma unroll 4
    for (int k = 0; k < HID; k += 4) {
        float4 a = *(const float4*)&s_act[wv][k];
        dot += a.x * sW[(k + 0) * HID + lane] + a.y * sW[(k + 1) * HID + lane]
             + a.z * sW[(k + 2) * HID + lane] + a.w * sW[(k + 3) * HID + lane];
    }
    g_next[(size_t)node * HID + lane] = (uchar)ftof8(dv * dot);
}

// ---------------------------------------------------------------------------
// B: aggregate g2 -> act2 = relu(dv*acc+b2) -> u2 = fp8(dv*act2). No LDS.
// ---------------------------------------------------------------------------
__global__ __launch_bounds__(256) void k_aggB(const uint* __restrict__ rowinfo,
                                              const uint* __restrict__ csr,
                                              const uint* __restrict__ gw,
                                              const float* __restrict__ dinv,
                                              const float* __restrict__ bias,
                                              uint* __restrict__ u2w) {
    const int tid = threadIdx.x;
    const int wv = tid >> 6, lane = tid & 63;
    const int node = blockIdx.x * 4 + wv;
    const uint ri  = rowinfo[node];
    const float dv = dinv[node];

    float4 acc = agg_row64(csr, gw, ri, node, lane);

    if ((lane >> 4) == 0) {
        const int sub = lane & 15;
        float4 b4 = ((const float4*)bias)[sub];
        uint p0 = ftof8(dv * fmaxf(dv * acc.x + b4.x, 0.f));
        uint p1 = ftof8(dv * fmaxf(dv * acc.y + b4.y, 0.f));
        uint p2 = ftof8(dv * fmaxf(dv * acc.z + b4.z, 0.f));
        uint p3 = ftof8(dv * fmaxf(dv * acc.w + b4.w, 0.f));
        u2w[((uint)node << 4) + sub] = p0 | (p1 << 8) | (p2 << 16) | (p3 << 24);
    }
}

// ---------------------------------------------------------------------------
// C: aggregate u2 -> z (64-wide) -> y = relu(dv*(z@W3)+b3) -> log_softmax
// ---------------------------------------------------------------------------
__global__ __launch_bounds__(256) void k_aggC(const uint* __restrict__ rowinfo,
                                              const uint* __restrict__ csr,
                                              const uint* __restrict__ gw,
                                              const float* __restrict__ dinv,
                                              const float* __restrict__ bias,
                                              const float* __restrict__ W,
                                              float* __restrict__ out) {
    __shared__ float sW[HID * OUT_C];     // 10 KB
    __shared__ float s_z[4][HID];
    const int tid = threadIdx.x;
    for (int i = tid; i < HID * OUT_C; i += 256) sW[i] = W[i];  // sync deferred

    const int wv = tid >> 6, lane = tid & 63;
    const int node = blockIdx.x * 4 + wv;
    const uint ri  = rowinfo[node];
    const float dv = dinv[node];

    float4 acc = agg_row64(csr, gw, ri, node, lane);

    if ((lane >> 4) == 0) ((float4*)&s_z[wv][0])[lane & 15] = acc;
    __syncthreads();

    const bool live = lane < OUT_C;
    float v = -INFINITY;
    if (live) {
        float dot = 0.0f;
#pragma unroll 4
        for (int k = 0; k < HID; k += 4) {
            float4 a = *(const float4*)&s_z[wv][k];
            dot += a.x * sW[(k + 0) * OUT_C + lane] + a.y * sW[(k + 1) * OUT_C + lane]
                 + a.z * sW[(k + 2) * OUT_C + lane] + a.w * sW[(k + 3) * OUT_C + lane];
        }
        v = fmaxf(dv * dot + bias[lane], 0.0f);
    }
    float mx = v;
#pragma unroll
    for (int off = 32; off > 0; off >>= 1) mx = fmaxf(mx, __shfl_xor(mx, off));
    float ex = live ? expf(v - mx) : 0.0f;
    float se = ex;
#pragma unroll
    for (int off = 32; off > 0; off >>= 1) se += __shfl_xor(se, off);
    if (live) out[(size_t)node * OUT_C + lane] = v - mx - logf(se);
}

// ---------------------------------------------------------------------------
// Launch
// ---------------------------------------------------------------------------
extern "C" void kernel_launch(void* const* d_in, const int* in_sizes, int n_in,
                              void* d_out, int out_size, void* d_ws, size_t ws_size,
                              hipStream_t stream) {
    const float* x  = (const float*)d_in[0];
    const int*   ei = (const int*)d_in[1];
    const float* w  = (const float*)d_in[2];
    const float* W1 = (const float*)d_in[3];
    const float* b1 = (const float*)d_in[4];
    const float* W2 = (const float*)d_in[5];
    const float* b2 = (const float*)d_in[6];
    const float* W3 = (const float*)d_in[7];
    const float* b3 = (const float*)d_in[8];
    float* out = (float*)d_out;

    char* ws = (char*)d_ws;
    size_t off = 0;
    auto carve = [&](size_t bytes) {
        char* p = ws + off;
        off += (bytes + 255) & ~(size_t)255;
        return p;
    };
    int*   bcursor = (int*)carve(NB * sizeof(int));
    uint*  rowinfo = (uint*)carve(N_NODES * sizeof(uint));
    float* dinv    = (float*)carve(N_NODES * sizeof(float));
    uint*  csr     = (uint*)carve(((size_t)NB * PBS + 64) * sizeof(uint));  // 11.0 MB
    uint2* tmp     = (uint2*)carve((size_t)NB * CAP * sizeof(uint2) + 256); // 16.05 MB
    // tmp dead after k_build; reuse for fp8 activation tables (64 B rows)
    uchar* g1 = (uchar*)tmp;                         // 3.2 MB
    uchar* g2 = g1 + (size_t)N_NODES * HID;          // 3.2 MB
    uchar* u2 = g1;                                  // g1 dead after k_aggA
    (void)ws_size;

    const int nbBin = (E_EDGES + TILE - 1) / TILE;   // 391
    const int nbN4  = N_NODES / 4;                   // 12500
    const int nbG1  = N_NODES / NPB;                 // 3125

    (void)hipMemsetAsync(bcursor, 0, NB * sizeof(int), stream);
    k_bin<<<nbBin, P1T, 0, stream>>>(ei, w, bcursor, tmp);
    k_build<<<NB, BNODES, 0, stream>>>(bcursor, tmp, rowinfo, dinv, csr);

    k_gemm1<<<nbG1, 256, 0, stream>>>(x, W1, dinv, g1);
    k_aggA<<<nbN4, 256, 0, stream>>>(rowinfo, csr, (const uint*)g1, dinv, b1, W2, g2);
    k_aggB<<<nbN4, 256, 0, stream>>>(rowinfo, csr, (const uint*)g2, dinv, b2, (uint*)u2);
    k_aggC<<<nbN4, 256, 0, stream>>>(rowinfo, csr, (const uint*)u2, dinv, b3, W3, out);
}